// Round 8
// baseline (764.695 us; speedup 1.0000x reference)
//
#include <hip/hip_runtime.h>

// Problem constants
#define B_        256
#define NUM_COLS_ 512
#define VOCAB_    100
#define D_        128
#define N_        131072      // 2*B*NUM_NODES
#define E_INT_    1048576     // N*8
#define MERGED_   65536       // B*NUM_NODES
#define LN_EPS_   1e-5f
#define LDP_      136         // padded LDS row (bf16): 128+8; 272B row = 17*16B
#define NBKT_     2048        // dst buckets (64 nodes each)
#define NREP_     8           // counter/buffer replicas (one per XCD via blockIdx&7)
#define CAPR_     128         // per-replica per-bucket capacity
#define BPAD_     64          // max per-bucket lst padding (x2 degree pad)

typedef __attribute__((ext_vector_type(8))) __bf16 bf16x8;
typedef __attribute__((ext_vector_type(8))) unsigned short ushort8;
typedef __attribute__((ext_vector_type(4))) float f32x4;

__device__ __forceinline__ unsigned short f2b(float f) {
  union { float f; unsigned int u; } c; c.f = f;
  unsigned int b = c.u + 0x7fffu + ((c.u >> 16) & 1u);   // RNE
  return (unsigned short)(b >> 16);
}
__device__ __forceinline__ float2 unpk(unsigned int v) {
  union { unsigned int u; float f; } a, b;
  a.u = v << 16; b.u = v & 0xffff0000u;
  return (float2){a.f, b.f};   // .x = even elem, .y = odd elem
}

// ---------------- embedding gather into hA (+ sentinels in BOTH buffers)
__global__ __launch_bounds__(256) void embed_kernel(const int* __restrict__ x,
                                                    const float* __restrict__ emb,
                                                    unsigned short* __restrict__ hA,
                                                    unsigned short* __restrict__ hB) {
  if (blockIdx.x == 8192) {                   // sentinel block
    int tid = threadIdx.x;
    ushort8 zz = (ushort8){0,0,0,0,0,0,0,0};
    ushort8 mm = (ushort8){0xFF7F,0xFF7F,0xFF7F,0xFF7F,0xFF7F,0xFF7F,0xFF7F,0xFF7F};
    if (tid < 16)      ((ushort8*)hA)[(size_t)N_ * 16 + tid] = zz;
    else if (tid < 32) ((ushort8*)hA)[(size_t)(N_ + 1) * 16 + (tid - 16)] = mm;
    else if (tid < 48) ((ushort8*)hB)[(size_t)N_ * 16 + (tid - 32)] = zz;
    else if (tid < 64) ((ushort8*)hB)[(size_t)(N_ + 1) * 16 + (tid - 48)] = mm;
    return;
  }
  int t = blockIdx.x * 256 + threadIdx.x;
  int row = t >> 4, q = t & 15;
  int col = row & 511;
  int tok = x[row];
  const float4* src = (const float4*)(emb + ((size_t)col * VOCAB_ + tok) * D_) + q * 2;
  float4 v0 = src[0], v1 = src[1];
  ushort8 u;
  u[0] = f2b(v0.x); u[1] = f2b(v0.y); u[2] = f2b(v0.z); u[3] = f2b(v0.w);
  u[4] = f2b(v1.x); u[5] = f2b(v1.y); u[6] = f2b(v1.z); u[7] = f2b(v1.w);
  ((ushort8*)hA)[(size_t)row * 16 + q] = u;
}

// ---------------- binning A: XCD-replicated counters + replica-partitioned buffer
__global__ __launch_bounds__(256) void binA_kernel(const int* __restrict__ ei,
                                                   int* __restrict__ bcnt,
                                                   unsigned int* __restrict__ bbuf) {
  int e = blockIdx.x * 256 + threadIdx.x;
  int rep = blockIdx.x & (NREP_ - 1);
  int s = ei[e], d = ei[E_INT_ + e];
  int b = d >> 6;
  int pos = atomicAdd(&bcnt[rep * NBKT_ + b], 1);
  if (pos < CAPR_)
    bbuf[((size_t)b * NREP_ + rep) * CAPR_ + pos] =
        ((unsigned int)(d & 63) << 17) | (unsigned int)s;
}

// ---------------- exclusive scan of padded bucket sizes
__global__ __launch_bounds__(256) void bscan_kernel(const int* __restrict__ bcnt,
                                                    int* __restrict__ bbase) {
  __shared__ int ls[256];
  int tid = threadIdx.x;
  int loc[8]; int sum = 0;
  #pragma unroll
  for (int j = 0; j < 8; ++j) {
    int b = tid * 8 + j;
    int v = 0;
    #pragma unroll
    for (int r = 0; r < NREP_; ++r) {
      int c = bcnt[r * NBKT_ + b]; c = c < CAPR_ ? c : CAPR_;
      v += c;
    }
    loc[j] = sum; sum += v + BPAD_;
  }
  ls[tid] = sum;
  __syncthreads();
  for (int off = 1; off < 256; off <<= 1) {
    int a = (tid >= off) ? ls[tid - off] : 0;
    __syncthreads();
    ls[tid] += a;
    __syncthreads();
  }
  int ex = ls[tid] - sum;
  #pragma unroll
  for (int j = 0; j < 8; ++j) bbase[tid * 8 + j] = ex + loc[j];
}

// ---------------- binning B: per-bucket local CSR (deg padded to x2)
__global__ __launch_bounds__(256) void binB_kernel(const int* __restrict__ bcnt,
                                                   const int* __restrict__ bbase,
                                                   const unsigned int* __restrict__ bbuf,
                                                   int* __restrict__ cntP,
                                                   int* __restrict__ start,
                                                   int* __restrict__ lst) {
  __shared__ unsigned int ebuf[NREP_ * CAPR_];
  __shared__ int rep_off[NREP_ + 1];
  __shared__ int lcnt[64], loff[64], lcur[64], lcc[64], spd[64];
  int b = blockIdx.x, tid = threadIdx.x;
  if (tid < 64) { lcnt[tid] = 0; lcur[tid] = 0; }
  if (tid == 0) {
    int s = 0;
    for (int r = 0; r < NREP_; ++r) {
      rep_off[r] = s;
      int c = bcnt[r * NBKT_ + b]; c = c < CAPR_ ? c : CAPR_;
      s += c;
    }
    rep_off[NREP_] = s;
  }
  __syncthreads();
  for (int r = 0; r < NREP_; ++r) {
    int c = rep_off[r + 1] - rep_off[r];
    const unsigned int* src = bbuf + ((size_t)b * NREP_ + r) * CAPR_;
    for (int i = tid; i < c; i += 256) {
      unsigned int v = src[i];
      ebuf[rep_off[r] + i] = v;
      atomicAdd(&lcnt[v >> 17], 1);
    }
  }
  __syncthreads();
  int cc = 0, pd = 0;
  if (tid < 64) {
    cc = lcnt[tid]; cc = cc < 64 ? cc : 64;
    pd = (cc + 1) & ~1;
    spd[tid] = pd;
  }
  __syncthreads();
  for (int off = 1; off < 64; off <<= 1) {
    int a = (tid < 64 && tid >= off) ? spd[tid - off] : 0;
    __syncthreads();
    if (tid < 64) spd[tid] += a;
    __syncthreads();
  }
  int bb = bbase[b];
  if (tid < 64) {
    int off = spd[tid] - pd;
    loff[tid] = off; lcc[tid] = cc;
    int node = b * 64 + tid;
    cntP[node] = pd;
    start[node] = bb + off;
  }
  __syncthreads();
  int total = rep_off[NREP_];
  for (int i = tid; i < total; i += 256) {
    unsigned int v = ebuf[i];
    int dl = v >> 17, src = v & 0x1FFFF;
    int p = atomicAdd(&lcur[dl], 1);
    if (p < lcc[dl]) lst[bb + loff[dl] + p] = src;
  }
  __syncthreads();
  if (tid < 64) {
    int base2 = bb + loff[tid];
    int pd2 = (lcc[tid] + 1) & ~1;
    for (int q = lcc[tid]; q < pd2; ++q) lst[base2 + q] = N_;   // sentinel
  }
}

// ---------------- edge-attr table
__global__ void ctab_kernel(const float* __restrict__ lt, const float* __restrict__ ew,
                            const float* __restrict__ eb, float* __restrict__ cTab) {
  int blk = blockIdx.x;                       // 0..75
  int i = blk / 38, r = blk % 38, c = threadIdx.x;
  float acc = eb[i * 128 + c];
  for (int k = 0; k < 8; ++k) acc += lt[r * 8 + k] * ew[(i * 8 + k) * 128 + c];
  cTab[((size_t)i * 38 + r) * 128 + c] = acc;
}

// ---------------- weight pre-transpose+convert
__global__ __launch_bounds__(256) void wtrans_kernel(const float* __restrict__ a,
                                                     const float* __restrict__ b,
                                                     const float* __restrict__ c,
                                                     const float* __restrict__ d,
                                                     unsigned short* __restrict__ wT) {
  int o = blockIdx.x * 256 + threadIdx.x;     // 512*256 = 8*16384
  int mi = o >> 14;
  const float* srcs[4] = {a, b, c, d};
  const float* p = srcs[mi >> 1] + (mi & 1) * 16384;
  int j = o & 16383, n = j >> 7, k = j & 127;
  wT[o] = f2b(p[k * 128 + n]);
}

// ---------------- gather phase of the fused layer (per quarter-wave, 8 nodes)
template <bool EA>
__device__ __forceinline__ void gather_phase(
    const uint4* __restrict__ h16, unsigned short* __restrict__ st,
    const int* __restrict__ start, const int* __restrict__ cntP,
    const int* __restrict__ lst, const float* __restrict__ ctb,
    const int* __restrict__ los, float eps,
    int rowbase, int wave, int qw, int ql, int lane) {
  float4 cA = (float4){0,0,0,0}, cB = (float4){0,0,0,0};
  if (EA) { cA = ((const float4*)ctb)[ql * 2]; cB = ((const float4*)ctb)[ql * 2 + 1]; }
  for (int s = 0; s < 8; ++s) {
    int node = rowbase + wave * 32 + qw * 8 + s;
    int pd = cntP[node], b = start[node];
    int idx[4];
    #pragma unroll
    for (int r = 0; r < 4; ++r) {
      int slot = r * 16 + ql;
      int v = (slot < pd) ? lst[b + slot] : N_;
      idx[r] = EA ? v + (v >> 17) : v;        // EA: sentinel N_ -> N_+1 (-big row)
    }
    float a[8] = {0.f,0.f,0.f,0.f,0.f,0.f,0.f,0.f};
    int it = pd >> 1;                         // pair count (pd even)
    for (int t = 0; t < it; t += 2) {
      int e[4];
      #pragma unroll
      for (int p = 0; p < 4; ++p) {
        int j = 2 * t + p;
        int r = j >> 4;
        int v = (r == 0) ? idx[0] : (r == 1) ? idx[1] : (r == 2) ? idx[2] : idx[3];
        e[p] = __shfl(v, (lane & 48) + (j & 15));
      }
      uint4 w0 = h16[(size_t)e[0] * 16 + ql];
      uint4 w1 = h16[(size_t)e[1] * 16 + ql];
      uint4 w2 = h16[(size_t)e[2] * 16 + ql];
      uint4 w3 = h16[(size_t)e[3] * 16 + ql];
      #pragma unroll
      for (int p = 0; p < 4; ++p) {
        uint4 v4 = p == 0 ? w0 : p == 1 ? w1 : p == 2 ? w2 : w3;
        float2 f0 = unpk(v4.x), f1 = unpk(v4.y), f2 = unpk(v4.z), f3 = unpk(v4.w);
        if (EA) {
          a[0] += fmaxf(f0.x + cA.x, 0.f); a[1] += fmaxf(f0.y + cA.y, 0.f);
          a[2] += fmaxf(f1.x + cA.z, 0.f); a[3] += fmaxf(f1.y + cA.w, 0.f);
          a[4] += fmaxf(f2.x + cB.x, 0.f); a[5] += fmaxf(f2.y + cB.y, 0.f);
          a[6] += fmaxf(f3.x + cB.z, 0.f); a[7] += fmaxf(f3.y + cB.w, 0.f);
        } else {
          a[0] += f0.x; a[1] += f0.y; a[2] += f1.x; a[3] += f1.y;
          a[4] += f2.x; a[5] += f2.y; a[6] += f3.x; a[7] += f3.y;
        }
      }
    }
    if (EA && node >= MERGED_) {              // extra self-edge j -> j+MERGED_
      int jS = node - MERGED_;
      int lt = los[jS >> 8];
      const float4* cr = (const float4*)(ctb + (size_t)lt * 128);
      float4 dA = cr[ql * 2], dB = cr[ql * 2 + 1];
      uint4 v4 = h16[(size_t)jS * 16 + ql];
      float2 f0 = unpk(v4.x), f1 = unpk(v4.y), f2 = unpk(v4.z), f3 = unpk(v4.w);
      a[0] += fmaxf(f0.x + dA.x, 0.f); a[1] += fmaxf(f0.y + dA.y, 0.f);
      a[2] += fmaxf(f1.x + dA.z, 0.f); a[3] += fmaxf(f1.y + dA.w, 0.f);
      a[4] += fmaxf(f2.x + dB.x, 0.f); a[5] += fmaxf(f2.y + dB.y, 0.f);
      a[6] += fmaxf(f3.x + dB.z, 0.f); a[7] += fmaxf(f3.y + dB.w, 0.f);
    }
    uint4 self = h16[(size_t)node * 16 + ql];
    float2 s0 = unpk(self.x), s1 = unpk(self.y), s2 = unpk(self.z), s3 = unpk(self.w);
    ushort8 u;
    u[0] = f2b(eps * s0.x + a[0]); u[1] = f2b(eps * s0.y + a[1]);
    u[2] = f2b(eps * s1.x + a[2]); u[3] = f2b(eps * s1.y + a[3]);
    u[4] = f2b(eps * s2.x + a[4]); u[5] = f2b(eps * s2.y + a[5]);
    u[6] = f2b(eps * s3.x + a[6]); u[7] = f2b(eps * s3.y + a[7]);
    *(ushort8*)&st[(wave * 32 + qw * 8 + s) * LDP_ + ql * 8] = u;
  }
}

// ---------------- fused layer: agg (gather) + MLP + optional group-sum
// mode bit0: write hout; bit1: gsum into osum; bit2: edge-attr (g2) gather
__global__ __launch_bounds__(256) void layer_kernel(
    const unsigned short* __restrict__ hin, unsigned short* __restrict__ hout,
    const int* __restrict__ start, const int* __restrict__ cntP,
    const int* __restrict__ lst,
    const unsigned short* __restrict__ w1g, const unsigned short* __restrict__ w2g,
    const float* __restrict__ b1, const float* __restrict__ gg,
    const float* __restrict__ be, const float* __restrict__ b2,
    const float* __restrict__ cTab, const int* __restrict__ los,
    const float* __restrict__ eps_ptr, int layer,
    float* __restrict__ osum, int mode) {
  __shared__ __align__(16) unsigned short st[128 * LDP_];  // z-tile, then t-matrix
  __shared__ float b1s[128], gs[128], bes[128], b2s[128], sred[128];

  int tid = threadIdx.x;
  if (tid < 128) {
    b1s[tid] = b1[tid]; gs[tid] = gg[tid]; bes[tid] = be[tid]; b2s[tid] = b2[tid];
    sred[tid] = 0.f;
  }
  int wave = tid >> 6, lane = tid & 63;
  int qw = lane >> 4, ql = lane & 15;
  int rowbase = blockIdx.x * 128;
  float eps = 1.0f + eps_ptr[layer];
  const float* ctb = cTab + (size_t)layer * 38 * 128;
  const uint4* h16 = (const uint4*)hin;

  if (mode & 4)
    gather_phase<true >(h16, st, start, cntP, lst, ctb, los, eps, rowbase, wave, qw, ql, lane);
  else
    gather_phase<false>(h16, st, start, cntP, lst, ctb, los, eps, rowbase, wave, qw, ql, lane);
  __syncthreads();   // z-tile complete; also orders b1s/sred init

  int quad = qw, m = ql;
  int rl0 = wave * 32;

  // A-frags for GEMM1 from LDS z-tile (wave-private rows)
  bf16x8 afr[2][4];
  #pragma unroll
  for (int rb = 0; rb < 2; ++rb)
    #pragma unroll
    for (int kc = 0; kc < 4; ++kc)
      afr[rb][kc] = __builtin_bit_cast(bf16x8,
          *(const ushort8*)&st[(rl0 + rb * 16 + m) * LDP_ + kc * 32 + quad * 8]);

  f32x4 acc[2][8];
  #pragma unroll
  for (int rb = 0; rb < 2; ++rb)
    #pragma unroll
    for (int cb = 0; cb < 8; ++cb)
      acc[rb][cb] = (f32x4){0.f, 0.f, 0.f, 0.f};

  #pragma unroll
  for (int kc = 0; kc < 4; ++kc) {
    #pragma unroll
    for (int cb = 0; cb < 8; ++cb) {
      bf16x8 bfr = __builtin_bit_cast(bf16x8,
          *(const ushort8*)(w1g + (cb * 16 + m) * 128 + kc * 32 + quad * 8));
      acc[0][cb] = __builtin_amdgcn_mfma_f32_16x16x32_bf16(afr[0][kc], bfr, acc[0][cb], 0, 0, 0);
      acc[1][cb] = __builtin_amdgcn_mfma_f32_16x16x32_bf16(afr[1][kc], bfr, acc[1][cb], 0, 0, 0);
    }
  }

  // bias + LN + ReLU
  #pragma unroll
  for (int rb = 0; rb < 2; ++rb) {
    #pragma unroll
    for (int reg = 0; reg < 4; ++reg) {
      float v[8]; float s1 = 0.f, s2 = 0.f;
      #pragma unroll
      for (int cb = 0; cb < 8; ++cb) {
        float xv = acc[rb][cb][reg] + b1s[cb * 16 + m];
        v[cb] = xv; s1 += xv; s2 += xv * xv;
      }
      #pragma unroll
      for (int off = 1; off < 16; off <<= 1) { s1 += __shfl_xor(s1, off); s2 += __shfl_xor(s2, off); }
      float mu  = s1 * (1.f / 128.f);
      float var = s2 * (1.f / 128.f) - mu * mu;
      float inv = rsqrtf(var + LN_EPS_);
      #pragma unroll
      for (int cb = 0; cb < 8; ++cb) {
        float xn = (v[cb] - mu) * inv * gs[cb * 16 + m] + bes[cb * 16 + m];
        acc[rb][cb][reg] = fmaxf(xn, 0.f);
      }
    }
  }

  // t-matrix into st (wave-private rows; per-wave LDS ordering suffices)
  #pragma unroll
  for (int rb = 0; rb < 2; ++rb)
    #pragma unroll
    for (int cb = 0; cb < 8; ++cb)
      #pragma unroll
      for (int reg = 0; reg < 4; ++reg)
        st[(rl0 + rb * 16 + quad * 4 + reg) * LDP_ + cb * 16 + m] = f2b(acc[rb][cb][reg]);

  bf16x8 afr2[2][4];
  #pragma unroll
  for (int rb = 0; rb < 2; ++rb)
    #pragma unroll
    for (int kc = 0; kc < 4; ++kc)
      afr2[rb][kc] = __builtin_bit_cast(bf16x8,
          *(const ushort8*)&st[(rl0 + rb * 16 + m) * LDP_ + kc * 32 + quad * 8]);

  f32x4 acc2[2][8];
  #pragma unroll
  for (int rb = 0; rb < 2; ++rb)
    #pragma unroll
    for (int cb = 0; cb < 8; ++cb)
      acc2[rb][cb] = (f32x4){0.f, 0.f, 0.f, 0.f};

  #pragma unroll
  for (int kc = 0; kc < 4; ++kc) {
    #pragma unroll
    for (int cb = 0; cb < 8; ++cb) {
      bf16x8 bfr = __builtin_bit_cast(bf16x8,
          *(const ushort8*)(w2g + (cb * 16 + m) * 128 + kc * 32 + quad * 8));
      acc2[0][cb] = __builtin_amdgcn_mfma_f32_16x16x32_bf16(afr2[0][kc], bfr, acc2[0][cb], 0, 0, 0);
      acc2[1][cb] = __builtin_amdgcn_mfma_f32_16x16x32_bf16(afr2[1][kc], bfr, acc2[1][cb], 0, 0, 0);
    }
  }

  float cs[8];
  #pragma unroll
  for (int cb = 0; cb < 8; ++cb) {
    int col = cb * 16 + m;
    float bb = b2s[col];
    float c = 0.f;
    #pragma unroll
    for (int rb = 0; rb < 2; ++rb)
      #pragma unroll
      for (int reg = 0; reg < 4; ++reg) {
        float v = acc2[rb][cb][reg] + bb;
        if (mode & 1) {
          size_t r = (size_t)rowbase + rl0 + rb * 16 + quad * 4 + reg;
          hout[r * 128 + col] = f2b(v);
        }
        c += v;
      }
    cs[cb] = c;
  }
  if (mode & 2) {
    #pragma unroll
    for (int cb = 0; cb < 8; ++cb) {
      float s = cs[cb];
      s += __shfl_xor(s, 16);
      s += __shfl_xor(s, 32);
      if (quad == 0) atomicAdd(&sred[cb * 16 + m], s);
    }
    __syncthreads();
    if (tid < 128) atomicAdd(&osum[(size_t)(blockIdx.x >> 1) * 256 + tid], sred[tid]);
  }
}

extern "C" void kernel_launch(void* const* d_in, const int* in_sizes, int n_in,
                              void* d_out, int out_size, void* d_ws, size_t ws_size,
                              hipStream_t stream) {
  const int*   x        = (const int*)d_in[0];
  const int*   ei       = (const int*)d_in[1];
  const int*   los      = (const int*)d_in[2];
  const float* emb      = (const float*)d_in[3];
  const float* lostab   = (const float*)d_in[4];
  const float* g1_w1    = (const float*)d_in[5];
  const float* g1_b1    = (const float*)d_in[6];
  const float* g1_g     = (const float*)d_in[7];
  const float* g1_be    = (const float*)d_in[8];
  const float* g1_w2    = (const float*)d_in[9];
  const float* g1_b2    = (const float*)d_in[10];
  const float* g1_eps   = (const float*)d_in[11];
  const float* g2_w1    = (const float*)d_in[12];
  const float* g2_b1    = (const float*)d_in[13];
  const float* g2_g     = (const float*)d_in[14];
  const float* g2_be    = (const float*)d_in[15];
  const float* g2_w2    = (const float*)d_in[16];
  const float* g2_b2    = (const float*)d_in[17];
  const float* g2_eps   = (const float*)d_in[18];
  const float* g2_ew    = (const float*)d_in[19];
  const float* g2_eb    = (const float*)d_in[20];
  float* out = (float*)d_out;

  char* ws = (char*)d_ws;
  unsigned short* hA  = (unsigned short*)(ws);                        // 33,555,456
  unsigned short* hB  = (unsigned short*)(ws + (size_t)33555456);     // 33,555,456
  // bbuf aliases hB's low 8.4 MB: binA/binB finish before L1 writes hB;
  // hB sentinels (at +33.55 MB) don't overlap bbuf.
  unsigned int* bbuf = (unsigned int*)(ws + (size_t)33555456);        // 8,388,608
  int* bcnt  = (int*)(ws + (size_t)67110912);                         // 65,536
  int* bbase = (int*)(ws + (size_t)67176448);                         // 8,192
  int* cntP  = (int*)(ws + (size_t)67184640);                         // 524,288
  int* start = (int*)(ws + (size_t)67708928);                         // 524,288
  float* cTab= (float*)(ws + (size_t)68233216);                       // 38,912
  unsigned short* wT = (unsigned short*)(ws + (size_t)68272128);      // 262,144
  int* lst   = (int*)(ws + (size_t)68534272);                         // 8,388,608 -> ends 76,922,880

  hipMemsetAsync(bcnt, 0, (size_t)NREP_ * NBKT_ * 4, stream);
  hipMemsetAsync(out, 0, (size_t)out_size * 4, stream);

  embed_kernel <<<8193, 256, 0, stream>>>(x, emb, hA, hB);
  binA_kernel  <<<4096, 256, 0, stream>>>(ei, bcnt, bbuf);
  bscan_kernel <<<1, 256, 0, stream>>>(bcnt, bbase);
  binB_kernel  <<<NBKT_, 256, 0, stream>>>(bcnt, bbase, bbuf, cntP, start, lst);
  ctab_kernel  <<<76, 128, 0, stream>>>(lostab, g2_ew, g2_eb, cTab);
  wtrans_kernel<<<512, 256, 0, stream>>>(g1_w1, g1_w2, g2_w1, g2_w2, wT);

  // L1: g1[0]  hA -> hB
  layer_kernel<<<1024, 256, 0, stream>>>(hA, hB, start, cntP, lst,
      wT + (size_t)0 * 16384, wT + (size_t)2 * 16384,
      g1_b1, g1_g, g1_be, g1_b2, cTab, los, g1_eps, 0, out, 1);
  // L2: g1[1]  hB -> hA, + gsum into out[:,0:128]
  layer_kernel<<<1024, 256, 0, stream>>>(hB, hA, start, cntP, lst,
      wT + (size_t)1 * 16384, wT + (size_t)3 * 16384,
      g1_b1 + 128, g1_g + 128, g1_be + 128, g1_b2 + 128, cTab, los, g1_eps, 1, out, 3);
  // L3: g2[0]  hA -> hB, edge-attr
  layer_kernel<<<1024, 256, 0, stream>>>(hA, hB, start, cntP, lst,
      wT + (size_t)4 * 16384, wT + (size_t)6 * 16384,
      g2_b1, g2_g, g2_be, g2_b2, cTab, los, g2_eps, 0, out + 128, 5);
  // L4: g2[1]  hB -> (none), edge-attr + gsum into out[:,128:256]
  layer_kernel<<<1024, 256, 0, stream>>>(hB, hA, start, cntP, lst,
      wT + (size_t)5 * 16384, wT + (size_t)7 * 16384,
      g2_b1 + 128, g2_g + 128, g2_be + 128, g2_b2 + 128, cTab, los, g2_eps, 1, out + 128, 6);
}

// Round 10
// 598.152 us; speedup vs baseline: 1.2784x; 1.2784x over previous
//
#include <hip/hip_runtime.h>

// Problem constants
#define B_        256
#define VOCAB_    100
#define D_        128
#define N_        131072      // 2*B*NUM_NODES
#define E_INT_    1048576     // N*8
#define MERGED_   65536       // B*NUM_NODES
#define LN_EPS_   1e-5f
#define LDP_      136         // padded LDS row (bf16): 128+8
#define NBKT_     2048        // dst buckets (64 nodes each)
#define NREP_     8           // counter/buffer replicas (one per XCD via blockIdx&7)
#define CAPR_     128         // per-replica per-bucket capacity
#define BPAD_     64          // max per-bucket lst padding (x2 degree pad)

typedef __attribute__((ext_vector_type(8))) __bf16 bf16x8;
typedef __attribute__((ext_vector_type(8))) unsigned short ushort8;
typedef __attribute__((ext_vector_type(4))) float f32x4;

__device__ __forceinline__ unsigned short f2b(float f) {
  union { float f; unsigned int u; } c; c.f = f;
  unsigned int b = c.u + 0x7fffu + ((c.u >> 16) & 1u);   // RNE
  return (unsigned short)(b >> 16);
}
__device__ __forceinline__ float2 unpk(unsigned int v) {
  union { unsigned int u; float f; } a, b;
  a.u = v << 16; b.u = v & 0xffff0000u;
  return (float2){a.f, b.f};
}

// ---------------- embedding gather (+ sentinel rows N_: zeros, N_+1: -big)
__global__ __launch_bounds__(256) void embed_kernel(const int* __restrict__ x,
                                                    const float* __restrict__ emb,
                                                    unsigned short* __restrict__ h) {
  if (blockIdx.x == 8192) {
    int tid = threadIdx.x;
    if (tid < 16) {
      ushort8 zz = (ushort8){0,0,0,0,0,0,0,0};
      ((ushort8*)h)[(size_t)N_ * 16 + tid] = zz;
    } else if (tid < 32) {
      ushort8 mm = (ushort8){0xFF7F,0xFF7F,0xFF7F,0xFF7F,0xFF7F,0xFF7F,0xFF7F,0xFF7F};
      ((ushort8*)h)[(size_t)(N_ + 1) * 16 + (tid - 16)] = mm;
    }
    return;
  }
  int t = blockIdx.x * 256 + threadIdx.x;
  int row = t >> 4, q = t & 15;
  int col = row & 511;
  int tok = x[row];
  const float4* src = (const float4*)(emb + ((size_t)col * VOCAB_ + tok) * D_) + q * 2;
  float4 v0 = src[0], v1 = src[1];
  ushort8 u;
  u[0] = f2b(v0.x); u[1] = f2b(v0.y); u[2] = f2b(v0.z); u[3] = f2b(v0.w);
  u[4] = f2b(v1.x); u[5] = f2b(v1.y); u[6] = f2b(v1.z); u[7] = f2b(v1.w);
  ((ushort8*)h)[(size_t)row * 16 + q] = u;
}

// ---------------- misc: wtrans + ctab + zero bcnt + zero out, one dispatch
__global__ __launch_bounds__(256) void misc_kernel(
    const float* __restrict__ w1a, const float* __restrict__ w2a,
    const float* __restrict__ w1b, const float* __restrict__ w2b,
    unsigned short* __restrict__ wT,
    const float* __restrict__ lt, const float* __restrict__ ew,
    const float* __restrict__ eb, float* __restrict__ cTab,
    int* __restrict__ bcnt, float* __restrict__ outz) {
  int blk = blockIdx.x, tid = threadIdx.x;
  if (blk < 512) {                            // wtrans: 512*256 = 8*16384
    int o = blk * 256 + tid;
    int mi = o >> 14;
    const float* srcs[4] = {w1a, w2a, w1b, w2b};
    const float* p = srcs[mi >> 1] + (mi & 1) * 16384;
    int j = o & 16383, n = j >> 7, k = j & 127;
    wT[o] = f2b(p[k * 128 + n]);
  } else if (blk < 588) {                     // ctab: 76 blocks, 128 threads active
    if (tid < 128) {
      int b2 = blk - 512;
      int i = b2 / 38, r = b2 % 38, c = tid;
      float acc = eb[i * 128 + c];
      for (int k = 0; k < 8; ++k) acc += lt[r * 8 + k] * ew[(i * 8 + k) * 128 + c];
      cTab[((size_t)i * 38 + r) * 128 + c] = acc;
    }
  } else if (blk < 652) {                     // zero bcnt: 64*256 = 16384
    bcnt[(blk - 588) * 256 + tid] = 0;
  } else {                                    // zero out: 512*256 = 131072
    outz[(size_t)(blk - 652) * 256 + tid] = 0.f;
  }
}

// ---------------- binning A: XCD-replicated counters + replica-partitioned buffer
__global__ __launch_bounds__(256) void binA_kernel(const int* __restrict__ ei,
                                                   int* __restrict__ bcnt,
                                                   unsigned int* __restrict__ bbuf) {
  int e = blockIdx.x * 256 + threadIdx.x;
  int rep = blockIdx.x & (NREP_ - 1);
  int s = ei[e], d = ei[E_INT_ + e];
  int b = d >> 6;
  int pos = atomicAdd(&bcnt[rep * NBKT_ + b], 1);
  if (pos < CAPR_)
    bbuf[((size_t)b * NREP_ + rep) * CAPR_ + pos] =
        ((unsigned int)(d & 63) << 17) | (unsigned int)s;
}

// ---------------- exclusive scan of padded bucket sizes
__global__ __launch_bounds__(256) void bscan_kernel(const int* __restrict__ bcnt,
                                                    int* __restrict__ bbase) {
  __shared__ int ls[256];
  int tid = threadIdx.x;
  int loc[8]; int sum = 0;
  #pragma unroll
  for (int j = 0; j < 8; ++j) {
    int b = tid * 8 + j;
    int v = 0;
    #pragma unroll
    for (int r = 0; r < NREP_; ++r) {
      int c = bcnt[r * NBKT_ + b]; c = c < CAPR_ ? c : CAPR_;
      v += c;
    }
    loc[j] = sum; sum += v + BPAD_;
  }
  ls[tid] = sum;
  __syncthreads();
  for (int off = 1; off < 256; off <<= 1) {
    int a = (tid >= off) ? ls[tid - off] : 0;
    __syncthreads();
    ls[tid] += a;
    __syncthreads();
  }
  int ex = ls[tid] - sum;
  #pragma unroll
  for (int j = 0; j < 8; ++j) bbase[tid * 8 + j] = ex + loc[j];
}

// ---------------- binning B: per-bucket local CSR (deg padded to x2)
__global__ __launch_bounds__(256) void binB_kernel(const int* __restrict__ bcnt,
                                                   const int* __restrict__ bbase,
                                                   const unsigned int* __restrict__ bbuf,
                                                   int* __restrict__ cntP,
                                                   int* __restrict__ start,
                                                   int* __restrict__ lst) {
  __shared__ unsigned int ebuf[NREP_ * CAPR_];
  __shared__ int rep_off[NREP_ + 1];
  __shared__ int lcnt[64], loff[64], lcur[64], lcc[64], spd[64];
  int b = blockIdx.x, tid = threadIdx.x;
  if (tid < 64) { lcnt[tid] = 0; lcur[tid] = 0; }
  if (tid == 0) {
    int s = 0;
    for (int r = 0; r < NREP_; ++r) {
      rep_off[r] = s;
      int c = bcnt[r * NBKT_ + b]; c = c < CAPR_ ? c : CAPR_;
      s += c;
    }
    rep_off[NREP_] = s;
  }
  __syncthreads();
  for (int r = 0; r < NREP_; ++r) {
    int c = rep_off[r + 1] - rep_off[r];
    const unsigned int* src = bbuf + ((size_t)b * NREP_ + r) * CAPR_;
    for (int i = tid; i < c; i += 256) {
      unsigned int v = src[i];
      ebuf[rep_off[r] + i] = v;
      atomicAdd(&lcnt[v >> 17], 1);
    }
  }
  __syncthreads();
  int cc = 0, pd = 0;
  if (tid < 64) {
    cc = lcnt[tid]; cc = cc < 64 ? cc : 64;
    pd = (cc + 1) & ~1;
    spd[tid] = pd;
  }
  __syncthreads();
  for (int off = 1; off < 64; off <<= 1) {
    int a = (tid < 64 && tid >= off) ? spd[tid - off] : 0;
    __syncthreads();
    if (tid < 64) spd[tid] += a;
    __syncthreads();
  }
  int bb = bbase[b];
  if (tid < 64) {
    int off = spd[tid] - pd;
    loff[tid] = off; lcc[tid] = cc;
    int node = b * 64 + tid;
    cntP[node] = pd;
    start[node] = bb + off;
  }
  __syncthreads();
  int total = rep_off[NREP_];
  for (int i = tid; i < total; i += 256) {
    unsigned int v = ebuf[i];
    int dl = v >> 17, src = v & 0x1FFFF;
    int p = atomicAdd(&lcur[dl], 1);
    if (p < lcc[dl]) lst[bb + loff[dl] + p] = src;
  }
  __syncthreads();
  if (tid < 64) {
    int base2 = bb + loff[tid];
    int pd2 = (lcc[tid] + 1) & ~1;
    for (int q = lcc[tid]; q < pd2; ++q) lst[base2 + q] = N_;   // sentinel
  }
}

// ---------------- loop-1 aggregation: one node per quarter-wave, dwordx4 rows
__global__ __launch_bounds__(256) void agg1_kernel(const unsigned short* __restrict__ h,
                                                   unsigned short* __restrict__ z,
                                                   const int* __restrict__ start,
                                                   const int* __restrict__ cntP,
                                                   const int* __restrict__ lst,
                                                   const float* __restrict__ eps_ptr,
                                                   int layer) {
  int tid = threadIdx.x;
  int wave = tid >> 6, lane = tid & 63;
  int qw = lane >> 4, ql = lane & 15;
  int node = (blockIdx.x * 4 + wave) * 4 + qw;
  float eps = 1.0f + eps_ptr[layer];
  int pd = cntP[node];
  int b = start[node];
  int idx[4];
  #pragma unroll
  for (int r = 0; r < 4; ++r) {
    int slot = r * 16 + ql;
    idx[r] = (slot < pd) ? lst[b + slot] : N_;
  }
  int it = pd >> 1;
  int itm = it;
  itm = max(itm, __shfl_xor(itm, 16));
  itm = max(itm, __shfl_xor(itm, 32));
  const uint4* h16 = (const uint4*)h;
  float a[8] = {0.f,0.f,0.f,0.f,0.f,0.f,0.f,0.f};
  for (int t = 0; t < itm; t += 2) {
    int e[4];
    #pragma unroll
    for (int p = 0; p < 4; ++p) {
      int j = 2 * t + p;
      int r = j >> 4;
      int v = (r == 0) ? idx[0] : (r == 1) ? idx[1] : (r == 2) ? idx[2] : idx[3];
      e[p] = __shfl(v, qw * 16 + (j & 15));
    }
    uint4 v0 = h16[(size_t)e[0] * 16 + ql];
    uint4 v1 = h16[(size_t)e[1] * 16 + ql];
    uint4 v2 = h16[(size_t)e[2] * 16 + ql];
    uint4 v3 = h16[(size_t)e[3] * 16 + ql];
    #pragma unroll
    for (int p = 0; p < 4; ++p) {
      uint4 v = p == 0 ? v0 : p == 1 ? v1 : p == 2 ? v2 : v3;
      float2 f0 = unpk(v.x), f1 = unpk(v.y), f2 = unpk(v.z), f3 = unpk(v.w);
      a[0] += f0.x; a[1] += f0.y; a[2] += f1.x; a[3] += f1.y;
      a[4] += f2.x; a[5] += f2.y; a[6] += f3.x; a[7] += f3.y;
    }
  }
  uint4 self = h16[(size_t)node * 16 + ql];
  float2 s0 = unpk(self.x), s1 = unpk(self.y), s2 = unpk(self.z), s3 = unpk(self.w);
  float o0 = eps * s0.x + a[0], o1 = eps * s0.y + a[1];
  float o2 = eps * s1.x + a[2], o3 = eps * s1.y + a[3];
  float o4 = eps * s2.x + a[4], o5 = eps * s2.y + a[5];
  float o6 = eps * s3.x + a[6], o7 = eps * s3.y + a[7];
  uint4 ov;
  ov.x = ((unsigned int)f2b(o1) << 16) | f2b(o0);
  ov.y = ((unsigned int)f2b(o3) << 16) | f2b(o2);
  ov.z = ((unsigned int)f2b(o5) << 16) | f2b(o4);
  ov.w = ((unsigned int)f2b(o7) << 16) | f2b(o6);
  ((uint4*)z)[(size_t)node * 16 + ql] = ov;
}

// ---------------- loop-2 aggregation: relu(h+c), sentinel remap -> -big row
__global__ __launch_bounds__(256) void agg2_kernel(const unsigned short* __restrict__ h,
                                                   unsigned short* __restrict__ z,
                                                   const int* __restrict__ start,
                                                   const int* __restrict__ cntP,
                                                   const int* __restrict__ lst,
                                                   const float* __restrict__ cTab,
                                                   const int* __restrict__ los,
                                                   const float* __restrict__ eps_ptr,
                                                   int layer) {
  int tid = threadIdx.x;
  int wave = tid >> 6, lane = tid & 63;
  int qw = lane >> 4, ql = lane & 15;
  int node = (blockIdx.x * 4 + wave) * 4 + qw;
  float eps = 1.0f + eps_ptr[layer];
  int pd = cntP[node];
  int b = start[node];
  int idx[4];
  #pragma unroll
  for (int r = 0; r < 4; ++r) {
    int slot = r * 16 + ql;
    int v = (slot < pd) ? lst[b + slot] : N_;
    idx[r] = v + (v >> 17);
  }
  int it = pd >> 1;
  int itm = it;
  itm = max(itm, __shfl_xor(itm, 16));
  itm = max(itm, __shfl_xor(itm, 32));
  const uint4* h16 = (const uint4*)h;
  const float4* ct = (const float4*)(cTab + (size_t)layer * 38 * 128);
  float4 cA = ct[ql * 2], cB = ct[ql * 2 + 1];
  float a[8] = {0.f,0.f,0.f,0.f,0.f,0.f,0.f,0.f};
  for (int t = 0; t < itm; t += 2) {
    int e[4];
    #pragma unroll
    for (int p = 0; p < 4; ++p) {
      int j = 2 * t + p;
      int r = j >> 4;
      int v = (r == 0) ? idx[0] : (r == 1) ? idx[1] : (r == 2) ? idx[2] : idx[3];
      e[p] = __shfl(v, qw * 16 + (j & 15));
    }
    uint4 v0 = h16[(size_t)e[0] * 16 + ql];
    uint4 v1 = h16[(size_t)e[1] * 16 + ql];
    uint4 v2 = h16[(size_t)e[2] * 16 + ql];
    uint4 v3 = h16[(size_t)e[3] * 16 + ql];
    #pragma unroll
    for (int p = 0; p < 4; ++p) {
      uint4 v = p == 0 ? v0 : p == 1 ? v1 : p == 2 ? v2 : v3;
      float2 f0 = unpk(v.x), f1 = unpk(v.y), f2 = unpk(v.z), f3 = unpk(v.w);
      a[0] += fmaxf(f0.x + cA.x, 0.f); a[1] += fmaxf(f0.y + cA.y, 0.f);
      a[2] += fmaxf(f1.x + cA.z, 0.f); a[3] += fmaxf(f1.y + cA.w, 0.f);
      a[4] += fmaxf(f2.x + cB.x, 0.f); a[5] += fmaxf(f2.y + cB.y, 0.f);
      a[6] += fmaxf(f3.x + cB.z, 0.f); a[7] += fmaxf(f3.y + cB.w, 0.f);
    }
  }
  if (node >= MERGED_) {
    int jS = node - MERGED_;
    int lt = los[jS >> 8];
    const float4* cr = (const float4*)(cTab + ((size_t)layer * 38 + lt) * 128);
    float4 dA = cr[ql * 2], dB = cr[ql * 2 + 1];
    uint4 v = h16[(size_t)jS * 16 + ql];
    float2 f0 = unpk(v.x), f1 = unpk(v.y), f2 = unpk(v.z), f3 = unpk(v.w);
    a[0] += fmaxf(f0.x + dA.x, 0.f); a[1] += fmaxf(f0.y + dA.y, 0.f);
    a[2] += fmaxf(f1.x + dA.z, 0.f); a[3] += fmaxf(f1.y + dA.w, 0.f);
    a[4] += fmaxf(f2.x + dB.x, 0.f); a[5] += fmaxf(f2.y + dB.y, 0.f);
    a[6] += fmaxf(f3.x + dB.z, 0.f); a[7] += fmaxf(f3.y + dB.w, 0.f);
  }
  uint4 self = h16[(size_t)node * 16 + ql];
  float2 s0 = unpk(self.x), s1 = unpk(self.y), s2 = unpk(self.z), s3 = unpk(self.w);
  float o0 = eps * s0.x + a[0], o1 = eps * s0.y + a[1];
  float o2 = eps * s1.x + a[2], o3 = eps * s1.y + a[3];
  float o4 = eps * s2.x + a[4], o5 = eps * s2.y + a[5];
  float o6 = eps * s3.x + a[6], o7 = eps * s3.y + a[7];
  uint4 ov;
  ov.x = ((unsigned int)f2b(o1) << 16) | f2b(o0);
  ov.y = ((unsigned int)f2b(o3) << 16) | f2b(o2);
  ov.z = ((unsigned int)f2b(o5) << 16) | f2b(o4);
  ov.w = ((unsigned int)f2b(o7) << 16) | f2b(o6);
  ((uint4*)z)[(size_t)node * 16 + ql] = ov;
}

// ---------------- fused MLP: barrier-free (B-frags from L2-hot global wT)
// mode bit0: write hout; bit1: gsum into osum
__global__ __launch_bounds__(256) void mlp_kernel(
    const unsigned short* __restrict__ zin, unsigned short* __restrict__ hout,
    const unsigned short* __restrict__ w1g, const unsigned short* __restrict__ w2g,
    const float* __restrict__ b1, const float* __restrict__ gg,
    const float* __restrict__ be, const float* __restrict__ b2,
    float* __restrict__ osum, int mode) {
  __shared__ __align__(16) unsigned short st[128 * LDP_];   // t-matrix only
  __shared__ float sred[128];

  int tid = threadIdx.x;
  int wave = tid >> 6, lane = tid & 63;
  int quad = lane >> 4, m = lane & 15;
  size_t row0 = (size_t)blockIdx.x * 128 + wave * 32;
  int rl0 = wave * 32;

  // per-lane epilogue/LN params (tiny, L2-hot, identical across blocks)
  float bb1[8], bg[8], bbe[8];
  #pragma unroll
  for (int cb = 0; cb < 8; ++cb) {
    bb1[cb] = b1[cb * 16 + m]; bg[cb] = gg[cb * 16 + m]; bbe[cb] = be[cb * 16 + m];
  }

  // A-frags for GEMM1 from global bf16 z
  bf16x8 afr[2][4];
  #pragma unroll
  for (int rb = 0; rb < 2; ++rb) {
    const unsigned short* pr = zin + (row0 + rb * 16 + m) * 128 + quad * 8;
    #pragma unroll
    for (int kc = 0; kc < 4; ++kc)
      afr[rb][kc] = __builtin_bit_cast(bf16x8, *(const ushort8*)(pr + kc * 32));
  }

  f32x4 acc[2][8];
  #pragma unroll
  for (int rb = 0; rb < 2; ++rb)
    #pragma unroll
    for (int cb = 0; cb < 8; ++cb)
      acc[rb][cb] = (f32x4){0.f, 0.f, 0.f, 0.f};

  #pragma unroll
  for (int kc = 0; kc < 4; ++kc) {
    #pragma unroll
    for (int cb = 0; cb < 8; ++cb) {
      bf16x8 bfr = __builtin_bit_cast(bf16x8,
          *(const ushort8*)(w1g + (cb * 16 + m) * 128 + kc * 32 + quad * 8));
      acc[0][cb] = __builtin_amdgcn_mfma_f32_16x16x32_bf16(afr[0][kc], bfr, acc[0][cb], 0, 0, 0);
      acc[1][cb] = __builtin_amdgcn_mfma_f32_16x16x32_bf16(afr[1][kc], bfr, acc[1][cb], 0, 0, 0);
    }
  }

  // bias + LN + ReLU
  #pragma unroll
  for (int rb = 0; rb < 2; ++rb) {
    #pragma unroll
    for (int reg = 0; reg < 4; ++reg) {
      float v[8]; float s1 = 0.f, s2 = 0.f;
      #pragma unroll
      for (int cb = 0; cb < 8; ++cb) {
        float xv = acc[rb][cb][reg] + bb1[cb];
        v[cb] = xv; s1 += xv; s2 += xv * xv;
      }
      #pragma unroll
      for (int off = 1; off < 16; off <<= 1) { s1 += __shfl_xor(s1, off); s2 += __shfl_xor(s2, off); }
      float mu  = s1 * (1.f / 128.f);
      float var = s2 * (1.f / 128.f) - mu * mu;
      float inv = rsqrtf(var + LN_EPS_);
      #pragma unroll
      for (int cb = 0; cb < 8; ++cb) {
        float xn = (v[cb] - mu) * inv * bg[cb] + bbe[cb];
        acc[rb][cb][reg] = fmaxf(xn, 0.f);
      }
    }
  }

  // t-matrix into st — wave-private rows, no barrier needed
  #pragma unroll
  for (int rb = 0; rb < 2; ++rb)
    #pragma unroll
    for (int cb = 0; cb < 8; ++cb)
      #pragma unroll
      for (int reg = 0; reg < 4; ++reg)
        st[(rl0 + rb * 16 + quad * 4 + reg) * LDP_ + cb * 16 + m] = f2b(acc[rb][cb][reg]);

  bf16x8 afr2[2][4];
  #pragma unroll
  for (int rb = 0; rb < 2; ++rb)
    #pragma unroll
    for (int kc = 0; kc < 4; ++kc)
      afr2[rb][kc] = __builtin_bit_cast(bf16x8,
          *(const ushort8*)&st[(rl0 + rb * 16 + m) * LDP_ + kc * 32 + quad * 8]);

  f32x4 acc2[2][8];
  #pragma unroll
  for (int rb = 0; rb < 2; ++rb)
    #pragma unroll
    for (int cb = 0; cb < 8; ++cb)
      acc2[rb][cb] = (f32x4){0.f, 0.f, 0.f, 0.f};

  #pragma unroll
  for (int kc = 0; kc < 4; ++kc) {
    #pragma unroll
    for (int cb = 0; cb < 8; ++cb) {
      bf16x8 bfr = __builtin_bit_cast(bf16x8,
          *(const ushort8*)(w2g + (cb * 16 + m) * 128 + kc * 32 + quad * 8));
      acc2[0][cb] = __builtin_amdgcn_mfma_f32_16x16x32_bf16(afr2[0][kc], bfr, acc2[0][cb], 0, 0, 0);
      acc2[1][cb] = __builtin_amdgcn_mfma_f32_16x16x32_bf16(afr2[1][kc], bfr, acc2[1][cb], 0, 0, 0);
    }
  }

  float cs[8];
  #pragma unroll
  for (int cb = 0; cb < 8; ++cb) {
    int col = cb * 16 + m;
    float bb = b2[col];
    float c = 0.f;
    #pragma unroll
    for (int rb = 0; rb < 2; ++rb)
      #pragma unroll
      for (int reg = 0; reg < 4; ++reg) {
        float v = acc2[rb][cb][reg] + bb;
        if (mode & 1) {
          size_t r = row0 + rb * 16 + quad * 4 + reg;
          hout[r * 128 + col] = f2b(v);
        }
        c += v;
      }
    cs[cb] = c;
  }
  if (mode & 2) {
    if (tid < 128) sred[tid] = 0.f;
    __syncthreads();
    #pragma unroll
    for (int cb = 0; cb < 8; ++cb) {
      float s = cs[cb];
      s += __shfl_xor(s, 16);
      s += __shfl_xor(s, 32);
      if (quad == 0) atomicAdd(&sred[cb * 16 + m], s);
    }
    __syncthreads();
    if (tid < 128) atomicAdd(&osum[(size_t)(blockIdx.x >> 1) * 256 + tid], sred[tid]);
  }
}

extern "C" void kernel_launch(void* const* d_in, const int* in_sizes, int n_in,
                              void* d_out, int out_size, void* d_ws, size_t ws_size,
                              hipStream_t stream) {
  const int*   x        = (const int*)d_in[0];
  const int*   ei       = (const int*)d_in[1];
  const int*   los      = (const int*)d_in[2];
  const float* emb      = (const float*)d_in[3];
  const float* lostab   = (const float*)d_in[4];
  const float* g1_w1    = (const float*)d_in[5];
  const float* g1_b1    = (const float*)d_in[6];
  const float* g1_g     = (const float*)d_in[7];
  const float* g1_be    = (const float*)d_in[8];
  const float* g1_w2    = (const float*)d_in[9];
  const float* g1_b2    = (const float*)d_in[10];
  const float* g1_eps   = (const float*)d_in[11];
  const float* g2_w1    = (const float*)d_in[12];
  const float* g2_b1    = (const float*)d_in[13];
  const float* g2_g     = (const float*)d_in[14];
  const float* g2_be    = (const float*)d_in[15];
  const float* g2_w2    = (const float*)d_in[16];
  const float* g2_b2    = (const float*)d_in[17];
  const float* g2_eps   = (const float*)d_in[18];
  const float* g2_ew    = (const float*)d_in[19];
  const float* g2_eb    = (const float*)d_in[20];
  float* out = (float*)d_out;

  char* ws = (char*)d_ws;
  unsigned short* h   = (unsigned short*)(ws);                        // 33,555,456
  unsigned short* z   = (unsigned short*)(ws + (size_t)33555456);     // 33,554,432
  unsigned int* bbuf = (unsigned int*)(ws + (size_t)33555456);        // aliases z
  int* bcnt  = (int*)(ws + (size_t)67109888);                         // 65,536
  int* bbase = (int*)(ws + (size_t)67175424);                         // 8,192
  int* cntP  = (int*)(ws + (size_t)67183616);                         // 524,288
  int* start = (int*)(ws + (size_t)67707904);                         // 524,288
  float* cTab= (float*)(ws + (size_t)68232192);                       // 38,912
  unsigned short* wT = (unsigned short*)(ws + (size_t)68271104);      // 262,144
  int* lst   = (int*)(ws + (size_t)68533248);                         // 8,388,608 -> ends 76,921,856

  misc_kernel <<<1164, 256, 0, stream>>>(g1_w1, g1_w2, g2_w1, g2_w2, wT,
                                         lostab, g2_ew, g2_eb, cTab, bcnt, out);
  embed_kernel<<<8193, 256, 0, stream>>>(x, emb, h);
  binA_kernel <<<4096, 256, 0, stream>>>(ei, bcnt, bbuf);
  bscan_kernel<<<1, 256, 0, stream>>>(bcnt, bbase);
  binB_kernel <<<NBKT_, 256, 0, stream>>>(bcnt, bbase, bbuf, cntP, start, lst);

  for (int i = 0; i < 2; ++i) {
    agg1_kernel<<<8192, 256, 0, stream>>>(h, z, start, cntP, lst, g1_eps, i);
    mlp_kernel <<<1024, 256, 0, stream>>>(z, h,
        wT + (size_t)i * 16384, wT + (size_t)(2 + i) * 16384,
        g1_b1 + i * 128, g1_g + i * 128, g1_be + i * 128, g1_b2 + i * 128,
        out, i == 1 ? 3 : 1);
  }

  for (int i = 0; i < 2; ++i) {
    agg2_kernel<<<8192, 256, 0, stream>>>(h, z, start, cntP, lst, cTab, los, g2_eps, i);
    mlp_kernel <<<1024, 256, 0, stream>>>(z, h,
        wT + (size_t)(4 + i) * 16384, wT + (size_t)(6 + i) * 16384,
        g2_b1 + i * 128, g2_g + i * 128, g2_be + i * 128, g2_b2 + i * 128,
        out + 128, i == 1 ? 2 : 1);
  }
}

// Round 11
// 467.169 us; speedup vs baseline: 1.6369x; 1.2804x over previous
//
#include <hip/hip_runtime.h>

// Problem constants
#define B_        256
#define VOCAB_    100
#define D_        128
#define N_        131072      // 2*B*NUM_NODES
#define E_INT_    1048576     // N*8
#define MERGED_   65536       // B*NUM_NODES
#define LN_EPS_   1e-5f
#define LDP_      136         // padded LDS row (bf16): 128+8
#define NBKT_     2048        // dst buckets (64 nodes each)
#define NREP_     8           // counter/buffer replicas (one per XCD via blockIdx&7)
#define CAPR_     128         // per-replica per-bucket capacity
#define BPAD_     64          // max per-bucket lst padding (x2 degree pad)

typedef __attribute__((ext_vector_type(8))) __bf16 bf16x8;
typedef __attribute__((ext_vector_type(8))) unsigned short ushort8;
typedef __attribute__((ext_vector_type(4))) float f32x4;

__device__ __forceinline__ unsigned short f2b(float f) {
  union { float f; unsigned int u; } c; c.f = f;
  unsigned int b = c.u + 0x7fffu + ((c.u >> 16) & 1u);   // RNE
  return (unsigned short)(b >> 16);
}
__device__ __forceinline__ float2 unpk(unsigned int v) {
  union { unsigned int u; float f; } a, b;
  a.u = v << 16; b.u = v & 0xffff0000u;
  return (float2){a.f, b.f};
}

// ---------------- embedding gather (+ sentinel rows N_: zeros, N_+1: -big)
__global__ __launch_bounds__(256) void embed_kernel(const int* __restrict__ x,
                                                    const float* __restrict__ emb,
                                                    unsigned short* __restrict__ h) {
  if (blockIdx.x == 8192) {
    int tid = threadIdx.x;
    if (tid < 16) {
      ushort8 zz = (ushort8){0,0,0,0,0,0,0,0};
      ((ushort8*)h)[(size_t)N_ * 16 + tid] = zz;
    } else if (tid < 32) {
      ushort8 mm = (ushort8){0xFF7F,0xFF7F,0xFF7F,0xFF7F,0xFF7F,0xFF7F,0xFF7F,0xFF7F};
      ((ushort8*)h)[(size_t)(N_ + 1) * 16 + (tid - 16)] = mm;
    }
    return;
  }
  int t = blockIdx.x * 256 + threadIdx.x;
  int row = t >> 4, q = t & 15;
  int col = row & 511;
  int tok = x[row];
  const float4* src = (const float4*)(emb + ((size_t)col * VOCAB_ + tok) * D_) + q * 2;
  float4 v0 = src[0], v1 = src[1];
  ushort8 u;
  u[0] = f2b(v0.x); u[1] = f2b(v0.y); u[2] = f2b(v0.z); u[3] = f2b(v0.w);
  u[4] = f2b(v1.x); u[5] = f2b(v1.y); u[6] = f2b(v1.z); u[7] = f2b(v1.w);
  ((ushort8*)h)[(size_t)row * 16 + q] = u;
}

// ---------------- misc: wtrans + ctab + zero bcnt + zero out, one dispatch
__global__ __launch_bounds__(256) void misc_kernel(
    const float* __restrict__ w1a, const float* __restrict__ w2a,
    const float* __restrict__ w1b, const float* __restrict__ w2b,
    unsigned short* __restrict__ wT,
    const float* __restrict__ lt, const float* __restrict__ ew,
    const float* __restrict__ eb, float* __restrict__ cTab,
    int* __restrict__ bcnt, float* __restrict__ outz) {
  int blk = blockIdx.x, tid = threadIdx.x;
  if (blk < 512) {                            // wtrans: 512*256 = 8*16384
    int o = blk * 256 + tid;
    int mi = o >> 14;
    const float* srcs[4] = {w1a, w2a, w1b, w2b};
    const float* p = srcs[mi >> 1] + (mi & 1) * 16384;
    int j = o & 16383, n = j >> 7, k = j & 127;
    wT[o] = f2b(p[k * 128 + n]);
  } else if (blk < 588) {                     // ctab: 76 blocks, 128 threads active
    if (tid < 128) {
      int b2 = blk - 512;
      int i = b2 / 38, r = b2 % 38, c = tid;
      float acc = eb[i * 128 + c];
      for (int k = 0; k < 8; ++k) acc += lt[r * 8 + k] * ew[(i * 8 + k) * 128 + c];
      cTab[((size_t)i * 38 + r) * 128 + c] = acc;
    }
  } else if (blk < 652) {                     // zero bcnt: 64*256 = 16384
    bcnt[(blk - 588) * 256 + tid] = 0;
  } else {                                    // zero out: 512*256 = 131072
    outz[(size_t)(blk - 652) * 256 + tid] = 0.f;
  }
}

// ---------------- binning A: XCD-replicated counters + replica-partitioned buffer
__global__ __launch_bounds__(256) void binA_kernel(const int* __restrict__ ei,
                                                   int* __restrict__ bcnt,
                                                   unsigned int* __restrict__ bbuf) {
  int e = blockIdx.x * 256 + threadIdx.x;
  int rep = blockIdx.x & (NREP_ - 1);
  int s = ei[e], d = ei[E_INT_ + e];
  int b = d >> 6;
  int pos = atomicAdd(&bcnt[rep * NBKT_ + b], 1);
  if (pos < CAPR_)
    bbuf[((size_t)b * NREP_ + rep) * CAPR_ + pos] =
        ((unsigned int)(d & 63) << 17) | (unsigned int)s;
}

// ---------------- exclusive scan of padded bucket sizes
__global__ __launch_bounds__(256) void bscan_kernel(const int* __restrict__ bcnt,
                                                    int* __restrict__ bbase) {
  __shared__ int ls[256];
  int tid = threadIdx.x;
  int loc[8]; int sum = 0;
  #pragma unroll
  for (int j = 0; j < 8; ++j) {
    int b = tid * 8 + j;
    int v = 0;
    #pragma unroll
    for (int r = 0; r < NREP_; ++r) {
      int c = bcnt[r * NBKT_ + b]; c = c < CAPR_ ? c : CAPR_;
      v += c;
    }
    loc[j] = sum; sum += v + BPAD_;
  }
  ls[tid] = sum;
  __syncthreads();
  for (int off = 1; off < 256; off <<= 1) {
    int a = (tid >= off) ? ls[tid - off] : 0;
    __syncthreads();
    ls[tid] += a;
    __syncthreads();
  }
  int ex = ls[tid] - sum;
  #pragma unroll
  for (int j = 0; j < 8; ++j) bbase[tid * 8 + j] = ex + loc[j];
}

// ---------------- binning B: per-bucket local CSR (deg padded to x2)
__global__ __launch_bounds__(256) void binB_kernel(const int* __restrict__ bcnt,
                                                   const int* __restrict__ bbase,
                                                   const unsigned int* __restrict__ bbuf,
                                                   int* __restrict__ cntP,
                                                   int* __restrict__ start,
                                                   int* __restrict__ lst) {
  __shared__ unsigned int ebuf[NREP_ * CAPR_];
  __shared__ int rep_off[NREP_ + 1];
  __shared__ int lcnt[64], loff[64], lcur[64], lcc[64], spd[64];
  int b = blockIdx.x, tid = threadIdx.x;
  if (tid < 64) { lcnt[tid] = 0; lcur[tid] = 0; }
  if (tid == 0) {
    int s = 0;
    for (int r = 0; r < NREP_; ++r) {
      rep_off[r] = s;
      int c = bcnt[r * NBKT_ + b]; c = c < CAPR_ ? c : CAPR_;
      s += c;
    }
    rep_off[NREP_] = s;
  }
  __syncthreads();
  for (int r = 0; r < NREP_; ++r) {
    int c = rep_off[r + 1] - rep_off[r];
    const unsigned int* src = bbuf + ((size_t)b * NREP_ + r) * CAPR_;
    for (int i = tid; i < c; i += 256) {
      unsigned int v = src[i];
      ebuf[rep_off[r] + i] = v;
      atomicAdd(&lcnt[v >> 17], 1);
    }
  }
  __syncthreads();
  int cc = 0, pd = 0;
  if (tid < 64) {
    cc = lcnt[tid]; cc = cc < 64 ? cc : 64;
    pd = (cc + 1) & ~1;
    spd[tid] = pd;
  }
  __syncthreads();
  for (int off = 1; off < 64; off <<= 1) {
    int a = (tid < 64 && tid >= off) ? spd[tid - off] : 0;
    __syncthreads();
    if (tid < 64) spd[tid] += a;
    __syncthreads();
  }
  int bb = bbase[b];
  if (tid < 64) {
    int off = spd[tid] - pd;
    loff[tid] = off; lcc[tid] = cc;
    int node = b * 64 + tid;
    cntP[node] = pd;
    start[node] = bb + off;
  }
  __syncthreads();
  int total = rep_off[NREP_];
  for (int i = tid; i < total; i += 256) {
    unsigned int v = ebuf[i];
    int dl = v >> 17, src = v & 0x1FFFF;
    int p = atomicAdd(&lcur[dl], 1);
    if (p < lcc[dl]) lst[bb + loff[dl] + p] = src;
  }
  __syncthreads();
  if (tid < 64) {
    int base2 = bb + loff[tid];
    int pd2 = (lcc[tid] + 1) & ~1;
    for (int q = lcc[tid]; q < pd2; ++q) lst[base2 + q] = N_;   // sentinel
  }
}

// ---------------- loop-1 aggregation: one node per quarter-wave, dwordx4 rows
__global__ __launch_bounds__(256) void agg1_kernel(const unsigned short* __restrict__ h,
                                                   unsigned short* __restrict__ z,
                                                   const int* __restrict__ start,
                                                   const int* __restrict__ cntP,
                                                   const int* __restrict__ lst,
                                                   const float* __restrict__ eps_ptr,
                                                   int layer) {
  int tid = threadIdx.x;
  int wave = tid >> 6, lane = tid & 63;
  int qw = lane >> 4, ql = lane & 15;
  int node = (blockIdx.x * 4 + wave) * 4 + qw;
  float eps = 1.0f + eps_ptr[layer];
  int pd = cntP[node];
  int b = start[node];
  int idx[4];
  #pragma unroll
  for (int r = 0; r < 4; ++r) {
    int slot = r * 16 + ql;
    idx[r] = (slot < pd) ? lst[b + slot] : N_;
  }
  int it = pd >> 1;
  int itm = it;
  itm = max(itm, __shfl_xor(itm, 16));
  itm = max(itm, __shfl_xor(itm, 32));
  const uint4* h16 = (const uint4*)h;
  float a[8] = {0.f,0.f,0.f,0.f,0.f,0.f,0.f,0.f};
  for (int t = 0; t < itm; t += 2) {
    int e[4];
    #pragma unroll
    for (int p = 0; p < 4; ++p) {
      int j = 2 * t + p;
      int r = j >> 4;
      int v = (r == 0) ? idx[0] : (r == 1) ? idx[1] : (r == 2) ? idx[2] : idx[3];
      e[p] = __shfl(v, qw * 16 + (j & 15));
    }
    uint4 v0 = h16[(size_t)e[0] * 16 + ql];
    uint4 v1 = h16[(size_t)e[1] * 16 + ql];
    uint4 v2 = h16[(size_t)e[2] * 16 + ql];
    uint4 v3 = h16[(size_t)e[3] * 16 + ql];
    #pragma unroll
    for (int p = 0; p < 4; ++p) {
      uint4 v = p == 0 ? v0 : p == 1 ? v1 : p == 2 ? v2 : v3;
      float2 f0 = unpk(v.x), f1 = unpk(v.y), f2 = unpk(v.z), f3 = unpk(v.w);
      a[0] += f0.x; a[1] += f0.y; a[2] += f1.x; a[3] += f1.y;
      a[4] += f2.x; a[5] += f2.y; a[6] += f3.x; a[7] += f3.y;
    }
  }
  uint4 self = h16[(size_t)node * 16 + ql];
  float2 s0 = unpk(self.x), s1 = unpk(self.y), s2 = unpk(self.z), s3 = unpk(self.w);
  float o0 = eps * s0.x + a[0], o1 = eps * s0.y + a[1];
  float o2 = eps * s1.x + a[2], o3 = eps * s1.y + a[3];
  float o4 = eps * s2.x + a[4], o5 = eps * s2.y + a[5];
  float o6 = eps * s3.x + a[6], o7 = eps * s3.y + a[7];
  uint4 ov;
  ov.x = ((unsigned int)f2b(o1) << 16) | f2b(o0);
  ov.y = ((unsigned int)f2b(o3) << 16) | f2b(o2);
  ov.z = ((unsigned int)f2b(o5) << 16) | f2b(o4);
  ov.w = ((unsigned int)f2b(o7) << 16) | f2b(o6);
  ((uint4*)z)[(size_t)node * 16 + ql] = ov;
}

// ---------------- loop-2 aggregation: relu(h+c), sentinel remap -> -big row
__global__ __launch_bounds__(256) void agg2_kernel(const unsigned short* __restrict__ h,
                                                   unsigned short* __restrict__ z,
                                                   const int* __restrict__ start,
                                                   const int* __restrict__ cntP,
                                                   const int* __restrict__ lst,
                                                   const float* __restrict__ cTab,
                                                   const int* __restrict__ los,
                                                   const float* __restrict__ eps_ptr,
                                                   int layer) {
  int tid = threadIdx.x;
  int wave = tid >> 6, lane = tid & 63;
  int qw = lane >> 4, ql = lane & 15;
  int node = (blockIdx.x * 4 + wave) * 4 + qw;
  float eps = 1.0f + eps_ptr[layer];
  int pd = cntP[node];
  int b = start[node];
  int idx[4];
  #pragma unroll
  for (int r = 0; r < 4; ++r) {
    int slot = r * 16 + ql;
    int v = (slot < pd) ? lst[b + slot] : N_;
    idx[r] = v + (v >> 17);
  }
  int it = pd >> 1;
  int itm = it;
  itm = max(itm, __shfl_xor(itm, 16));
  itm = max(itm, __shfl_xor(itm, 32));
  const uint4* h16 = (const uint4*)h;
  const float4* ct = (const float4*)(cTab + (size_t)layer * 38 * 128);
  float4 cA = ct[ql * 2], cB = ct[ql * 2 + 1];
  float a[8] = {0.f,0.f,0.f,0.f,0.f,0.f,0.f,0.f};
  for (int t = 0; t < itm; t += 2) {
    int e[4];
    #pragma unroll
    for (int p = 0; p < 4; ++p) {
      int j = 2 * t + p;
      int r = j >> 4;
      int v = (r == 0) ? idx[0] : (r == 1) ? idx[1] : (r == 2) ? idx[2] : idx[3];
      e[p] = __shfl(v, qw * 16 + (j & 15));
    }
    uint4 v0 = h16[(size_t)e[0] * 16 + ql];
    uint4 v1 = h16[(size_t)e[1] * 16 + ql];
    uint4 v2 = h16[(size_t)e[2] * 16 + ql];
    uint4 v3 = h16[(size_t)e[3] * 16 + ql];
    #pragma unroll
    for (int p = 0; p < 4; ++p) {
      uint4 v = p == 0 ? v0 : p == 1 ? v1 : p == 2 ? v2 : v3;
      float2 f0 = unpk(v.x), f1 = unpk(v.y), f2 = unpk(v.z), f3 = unpk(v.w);
      a[0] += fmaxf(f0.x + cA.x, 0.f); a[1] += fmaxf(f0.y + cA.y, 0.f);
      a[2] += fmaxf(f1.x + cA.z, 0.f); a[3] += fmaxf(f1.y + cA.w, 0.f);
      a[4] += fmaxf(f2.x + cB.x, 0.f); a[5] += fmaxf(f2.y + cB.y, 0.f);
      a[6] += fmaxf(f3.x + cB.z, 0.f); a[7] += fmaxf(f3.y + cB.w, 0.f);
    }
  }
  if (node >= MERGED_) {
    int jS = node - MERGED_;
    int lt = los[jS >> 8];
    const float4* cr = (const float4*)(cTab + ((size_t)layer * 38 + lt) * 128);
    float4 dA = cr[ql * 2], dB = cr[ql * 2 + 1];
    uint4 v = h16[(size_t)jS * 16 + ql];
    float2 f0 = unpk(v.x), f1 = unpk(v.y), f2 = unpk(v.z), f3 = unpk(v.w);
    a[0] += fmaxf(f0.x + dA.x, 0.f); a[1] += fmaxf(f0.y + dA.y, 0.f);
    a[2] += fmaxf(f1.x + dA.z, 0.f); a[3] += fmaxf(f1.y + dA.w, 0.f);
    a[4] += fmaxf(f2.x + dB.x, 0.f); a[5] += fmaxf(f2.y + dB.y, 0.f);
    a[6] += fmaxf(f3.x + dB.z, 0.f); a[7] += fmaxf(f3.y + dB.w, 0.f);
  }
  uint4 self = h16[(size_t)node * 16 + ql];
  float2 s0 = unpk(self.x), s1 = unpk(self.y), s2 = unpk(self.z), s3 = unpk(self.w);
  float o0 = eps * s0.x + a[0], o1 = eps * s0.y + a[1];
  float o2 = eps * s1.x + a[2], o3 = eps * s1.y + a[3];
  float o4 = eps * s2.x + a[4], o5 = eps * s2.y + a[5];
  float o6 = eps * s3.x + a[6], o7 = eps * s3.y + a[7];
  uint4 ov;
  ov.x = ((unsigned int)f2b(o1) << 16) | f2b(o0);
  ov.y = ((unsigned int)f2b(o3) << 16) | f2b(o2);
  ov.z = ((unsigned int)f2b(o5) << 16) | f2b(o4);
  ov.w = ((unsigned int)f2b(o7) << 16) | f2b(o6);
  ((uint4*)z)[(size_t)node * 16 + ql] = ov;
}

// ---------------- fused MLP (R7-proven: LDS-staged weights, t reuses w1t)
// mode bit0: write hout; bit1: gsum into osum
__global__ __launch_bounds__(256, 2) void mlp_kernel(
    const unsigned short* __restrict__ zin, unsigned short* __restrict__ hout,
    const unsigned short* __restrict__ w1g, const unsigned short* __restrict__ w2g,
    const float* __restrict__ b1, const float* __restrict__ gg,
    const float* __restrict__ be, const float* __restrict__ b2,
    float* __restrict__ osum, int mode) {
  __shared__ __align__(16) unsigned short w1t[128 * LDP_];  // w1^T; reused for t
  __shared__ __align__(16) unsigned short w2t[128 * LDP_];
  __shared__ float b1s[128], gs[128], bes[128], b2s[128], sred[128];

  int tid = threadIdx.x;
  #pragma unroll
  for (int it = 0; it < 8; ++it) {
    int flat = it * 2048 + tid * 8;
    int n = flat >> 7, k = flat & 127;
    *(ushort8*)&w1t[n * LDP_ + k] = *(const ushort8*)(w1g + flat);
    *(ushort8*)&w2t[n * LDP_ + k] = *(const ushort8*)(w2g + flat);
  }
  if (tid < 128) {
    b1s[tid] = b1[tid]; gs[tid] = gg[tid]; bes[tid] = be[tid]; b2s[tid] = b2[tid];
    sred[tid] = 0.f;
  }

  int wave = tid >> 6, lane = tid & 63;
  int quad = lane >> 4, m = lane & 15;
  size_t row0 = (size_t)blockIdx.x * 128 + wave * 32;

  // A-frags for GEMM1 from global bf16 z (overlaps the LDS staging above)
  bf16x8 afr[2][4];
  #pragma unroll
  for (int rb = 0; rb < 2; ++rb) {
    const unsigned short* pr = zin + (row0 + rb * 16 + m) * 128 + quad * 8;
    #pragma unroll
    for (int kc = 0; kc < 4; ++kc)
      afr[rb][kc] = __builtin_bit_cast(bf16x8, *(const ushort8*)(pr + kc * 32));
  }
  __syncthreads();

  f32x4 acc[2][8];
  #pragma unroll
  for (int rb = 0; rb < 2; ++rb)
    #pragma unroll
    for (int cb = 0; cb < 8; ++cb)
      acc[rb][cb] = (f32x4){0.f, 0.f, 0.f, 0.f};

  #pragma unroll
  for (int kc = 0; kc < 4; ++kc) {
    #pragma unroll
    for (int cb = 0; cb < 8; ++cb) {
      bf16x8 bfr = __builtin_bit_cast(bf16x8,
          *(const ushort8*)&w1t[(cb * 16 + m) * LDP_ + kc * 32 + quad * 8]);
      acc[0][cb] = __builtin_amdgcn_mfma_f32_16x16x32_bf16(afr[0][kc], bfr, acc[0][cb], 0, 0, 0);
      acc[1][cb] = __builtin_amdgcn_mfma_f32_16x16x32_bf16(afr[1][kc], bfr, acc[1][cb], 0, 0, 0);
    }
  }

  // bias + LN + ReLU
  #pragma unroll
  for (int rb = 0; rb < 2; ++rb) {
    #pragma unroll
    for (int reg = 0; reg < 4; ++reg) {
      float v[8]; float s1 = 0.f, s2 = 0.f;
      #pragma unroll
      for (int cb = 0; cb < 8; ++cb) {
        float xv = acc[rb][cb][reg] + b1s[cb * 16 + m];
        v[cb] = xv; s1 += xv; s2 += xv * xv;
      }
      #pragma unroll
      for (int off = 1; off < 16; off <<= 1) { s1 += __shfl_xor(s1, off); s2 += __shfl_xor(s2, off); }
      float mu  = s1 * (1.f / 128.f);
      float var = s2 * (1.f / 128.f) - mu * mu;
      float inv = rsqrtf(var + LN_EPS_);
      #pragma unroll
      for (int cb = 0; cb < 8; ++cb) {
        float xn = (v[cb] - mu) * inv * gs[cb * 16 + m] + bes[cb * 16 + m];
        acc[rb][cb][reg] = fmaxf(xn, 0.f);
      }
    }
  }

  __syncthreads();   // all waves done reading w1t -> reuse for t
  int rl0 = wave * 32;
  #pragma unroll
  for (int rb = 0; rb < 2; ++rb)
    #pragma unroll
    for (int cb = 0; cb < 8; ++cb)
      #pragma unroll
      for (int reg = 0; reg < 4; ++reg)
        w1t[(rl0 + rb * 16 + quad * 4 + reg) * LDP_ + cb * 16 + m] = f2b(acc[rb][cb][reg]);

  // t rows are wave-private: no barrier needed before re-reading them
  bf16x8 afr2[2][4];
  #pragma unroll
  for (int rb = 0; rb < 2; ++rb)
    #pragma unroll
    for (int kc = 0; kc < 4; ++kc)
      afr2[rb][kc] = __builtin_bit_cast(bf16x8,
          *(const ushort8*)&w1t[(rl0 + rb * 16 + m) * LDP_ + kc * 32 + quad * 8]);

  f32x4 acc2[2][8];
  #pragma unroll
  for (int rb = 0; rb < 2; ++rb)
    #pragma unroll
    for (int cb = 0; cb < 8; ++cb)
      acc2[rb][cb] = (f32x4){0.f, 0.f, 0.f, 0.f};

  #pragma unroll
  for (int kc = 0; kc < 4; ++kc) {
    #pragma unroll
    for (int cb = 0; cb < 8; ++cb) {
      bf16x8 bfr = __builtin_bit_cast(bf16x8,
          *(const ushort8*)&w2t[(cb * 16 + m) * LDP_ + kc * 32 + quad * 8]);
      acc2[0][cb] = __builtin_amdgcn_mfma_f32_16x16x32_bf16(afr2[0][kc], bfr, acc2[0][cb], 0, 0, 0);
      acc2[1][cb] = __builtin_amdgcn_mfma_f32_16x16x32_bf16(afr2[1][kc], bfr, acc2[1][cb], 0, 0, 0);
    }
  }

  float cs[8];
  #pragma unroll
  for (int cb = 0; cb < 8; ++cb) {
    int col = cb * 16 + m;
    float bb = b2s[col];
    float c = 0.f;
    #pragma unroll
    for (int rb = 0; rb < 2; ++rb)
      #pragma unroll
      for (int reg = 0; reg < 4; ++reg) {
        float v = acc2[rb][cb][reg] + bb;
        if (mode & 1) {
          size_t r = row0 + rb * 16 + quad * 4 + reg;
          hout[r * 128 + col] = f2b(v);
        }
        c += v;
      }
    cs[cb] = c;
  }
  if (mode & 2) {
    #pragma unroll
    for (int cb = 0; cb < 8; ++cb) {
      float s = cs[cb];
      s += __shfl_xor(s, 16);
      s += __shfl_xor(s, 32);
      if (quad == 0) atomicAdd(&sred[cb * 16 + m], s);
    }
    __syncthreads();
    if (tid < 128) atomicAdd(&osum[(size_t)(blockIdx.x >> 1) * 256 + tid], sred[tid]);
  }
}

extern "C" void kernel_launch(void* const* d_in, const int* in_sizes, int n_in,
                              void* d_out, int out_size, void* d_ws, size_t ws_size,
                              hipStream_t stream) {
  const int*   x        = (const int*)d_in[0];
  const int*   ei       = (const int*)d_in[1];
  const int*   los      = (const int*)d_in[2];
  const float* emb      = (const float*)d_in[3];
  const float* lostab   = (const float*)d_in[4];
  const float* g1_w1    = (const float*)d_in[5];
  const float* g1_b1    = (const float*)d_in[6];
  const float* g1_g     = (const float*)d_in[7];
  const float* g1_be    = (const float*)d_in[8];
  const float* g1_w2    = (const float*)d_in[9];
  const float* g1_b2    = (const float*)d_in[10];
  const float* g1_eps   = (const float*)d_in[11];
  const float* g2_w1    = (const float*)d_in[12];
  const float* g2_b1    = (const float*)d_in[13];
  const float* g2_g     = (const float*)d_in[14];
  const float* g2_be    = (const float*)d_in[15];
  const float* g2_w2    = (const float*)d_in[16];
  const float* g2_b2    = (const float*)d_in[17];
  const float* g2_eps   = (const float*)d_in[18];
  const float* g2_ew    = (const float*)d_in[19];
  const float* g2_eb    = (const float*)d_in[20];
  float* out = (float*)d_out;

  char* ws = (char*)d_ws;
  unsigned short* h   = (unsigned short*)(ws);                        // 33,555,456
  unsigned short* z   = (unsigned short*)(ws + (size_t)33555456);     // 33,554,432
  unsigned int* bbuf = (unsigned int*)(ws + (size_t)33555456);        // aliases z
  int* bcnt  = (int*)(ws + (size_t)67109888);                         // 65,536
  int* bbase = (int*)(ws + (size_t)67175424);                         // 8,192
  int* cntP  = (int*)(ws + (size_t)67183616);                         // 524,288
  int* start = (int*)(ws + (size_t)67707904);                         // 524,288
  float* cTab= (float*)(ws + (size_t)68232192);                       // 38,912
  unsigned short* wT = (unsigned short*)(ws + (size_t)68271104);      // 262,144
  int* lst   = (int*)(ws + (size_t)68533248);                         // 8,388,608 -> ends 76,921,856

  misc_kernel <<<1164, 256, 0, stream>>>(g1_w1, g1_w2, g2_w1, g2_w2, wT,
                                         lostab, g2_ew, g2_eb, cTab, bcnt, out);
  embed_kernel<<<8193, 256, 0, stream>>>(x, emb, h);
  binA_kernel <<<4096, 256, 0, stream>>>(ei, bcnt, bbuf);
  bscan_kernel<<<1, 256, 0, stream>>>(bcnt, bbase);
  binB_kernel <<<NBKT_, 256, 0, stream>>>(bcnt, bbase, bbuf, cntP, start, lst);

  for (int i = 0; i < 2; ++i) {
    agg1_kernel<<<8192, 256, 0, stream>>>(h, z, start, cntP, lst, g1_eps, i);
    mlp_kernel <<<1024, 256, 0, stream>>>(z, h,
        wT + (size_t)i * 16384, wT + (size_t)(2 + i) * 16384,
        g1_b1 + i * 128, g1_g + i * 128, g1_be + i * 128, g1_b2 + i * 128,
        out, i == 1 ? 3 : 1);
  }

  for (int i = 0; i < 2; ++i) {
    agg2_kernel<<<8192, 256, 0, stream>>>(h, z, start, cntP, lst, cTab, los, g2_eps, i);
    mlp_kernel <<<1024, 256, 0, stream>>>(z, h,
        wT + (size_t)(4 + i) * 16384, wT + (size_t)(6 + i) * 16384,
        g2_b1 + i * 128, g2_g + i * 128, g2_be + i * 128, g2_b2 + i * 128,
        out + 128, i == 1 ? 2 : 1);
  }
}

// Round 12
// 462.954 us; speedup vs baseline: 1.6518x; 1.0091x over previous
//
#include <hip/hip_runtime.h>

// Problem constants
#define B_        256
#define VOCAB_    100
#define D_        128
#define N_        131072      // 2*B*NUM_NODES
#define E_INT_    1048576     // N*8
#define MERGED_   65536       // B*NUM_NODES
#define LN_EPS_   1e-5f
#define LDP_      136         // padded LDS row (bf16): 128+8
#define NBKT_     2048        // dst buckets (64 nodes each)
#define NREP_     8           // counter/buffer replicas (one per XCD via block&7)
#define CAPR_     128         // per-replica per-bucket capacity
#define BPAD_     64          // max per-bucket lst padding (x2 degree pad)

typedef __attribute__((ext_vector_type(8))) __bf16 bf16x8;
typedef __attribute__((ext_vector_type(8))) unsigned short ushort8;
typedef __attribute__((ext_vector_type(4))) float f32x4;

__device__ __forceinline__ unsigned short f2b(float f) {
  union { float f; unsigned int u; } c; c.f = f;
  unsigned int b = c.u + 0x7fffu + ((c.u >> 16) & 1u);   // RNE
  return (unsigned short)(b >> 16);
}
__device__ __forceinline__ float2 unpk(unsigned int v) {
  union { unsigned int u; float f; } a, b;
  a.u = v << 16; b.u = v & 0xffff0000u;
  return (float2){a.f, b.f};
}

// ---------------- setup: wtrans + ctab + zero out + embed + binA, one dispatch
// (bcnt is zeroed by hipMemsetAsync BEFORE this dispatch; all roles independent)
__global__ __launch_bounds__(256) void setup_kernel(
    const float* __restrict__ w1a, const float* __restrict__ w2a,
    const float* __restrict__ w1b, const float* __restrict__ w2b,
    unsigned short* __restrict__ wT,
    const float* __restrict__ lt, const float* __restrict__ ew,
    const float* __restrict__ eb, float* __restrict__ cTab,
    float* __restrict__ outz,
    const int* __restrict__ x, const float* __restrict__ emb,
    unsigned short* __restrict__ h,
    const int* __restrict__ ei, int* __restrict__ bcnt,
    unsigned int* __restrict__ bbuf) {
  int blk = blockIdx.x, tid = threadIdx.x;
  if (blk < 512) {                            // wtrans: 512*256 = 8*16384
    int o = blk * 256 + tid;
    int mi = o >> 14;
    const float* srcs[4] = {w1a, w2a, w1b, w2b};
    const float* p = srcs[mi >> 1] + (mi & 1) * 16384;
    int j = o & 16383, n = j >> 7, k = j & 127;
    wT[o] = f2b(p[k * 128 + n]);
  } else if (blk < 588) {                     // ctab: 76 blocks, 128 threads active
    if (tid < 128) {
      int b2 = blk - 512;
      int i = b2 / 38, r = b2 % 38, c = tid;
      float acc = eb[i * 128 + c];
      for (int k = 0; k < 8; ++k) acc += lt[r * 8 + k] * ew[(i * 8 + k) * 128 + c];
      cTab[((size_t)i * 38 + r) * 128 + c] = acc;
    }
  } else if (blk < 1100) {                    // zero out: 512*256 = 131072
    outz[(size_t)(blk - 588) * 256 + tid] = 0.f;
  } else if (blk < 9293) {                    // embed: 8193 blocks (+ sentinels)
    int ebk = blk - 1100;
    if (ebk == 8192) {
      if (tid < 16) {
        ushort8 zz = (ushort8){0,0,0,0,0,0,0,0};
        ((ushort8*)h)[(size_t)N_ * 16 + tid] = zz;
      } else if (tid < 32) {
        ushort8 mm = (ushort8){0xFF7F,0xFF7F,0xFF7F,0xFF7F,0xFF7F,0xFF7F,0xFF7F,0xFF7F};
        ((ushort8*)h)[(size_t)(N_ + 1) * 16 + (tid - 16)] = mm;
      }
      return;
    }
    int t = ebk * 256 + tid;
    int row = t >> 4, q = t & 15;
    int col = row & 511;
    int tok = x[row];
    const float4* src = (const float4*)(emb + ((size_t)col * VOCAB_ + tok) * D_) + q * 2;
    float4 v0 = src[0], v1 = src[1];
    ushort8 u;
    u[0] = f2b(v0.x); u[1] = f2b(v0.y); u[2] = f2b(v0.z); u[3] = f2b(v0.w);
    u[4] = f2b(v1.x); u[5] = f2b(v1.y); u[6] = f2b(v1.z); u[7] = f2b(v1.w);
    ((ushort8*)h)[(size_t)row * 16 + q] = u;
  } else {                                    // binA: 4096 blocks
    int ab = blk - 9293;
    int e = ab * 256 + tid;
    int rep = ab & (NREP_ - 1);               // ~XCD-local replica
    int s = ei[e], d = ei[E_INT_ + e];
    int b = d >> 6;
    int pos = atomicAdd(&bcnt[rep * NBKT_ + b], 1);
    if (pos < CAPR_)
      bbuf[((size_t)b * NREP_ + rep) * CAPR_ + pos] =
          ((unsigned int)(d & 63) << 17) | (unsigned int)s;
  }
}

// ---------------- exclusive scan of padded bucket sizes
__global__ __launch_bounds__(256) void bscan_kernel(const int* __restrict__ bcnt,
                                                    int* __restrict__ bbase) {
  __shared__ int ls[256];
  int tid = threadIdx.x;
  int loc[8]; int sum = 0;
  #pragma unroll
  for (int j = 0; j < 8; ++j) {
    int b = tid * 8 + j;
    int v = 0;
    #pragma unroll
    for (int r = 0; r < NREP_; ++r) {
      int c = bcnt[r * NBKT_ + b]; c = c < CAPR_ ? c : CAPR_;
      v += c;
    }
    loc[j] = sum; sum += v + BPAD_;
  }
  ls[tid] = sum;
  __syncthreads();
  for (int off = 1; off < 256; off <<= 1) {
    int a = (tid >= off) ? ls[tid - off] : 0;
    __syncthreads();
    ls[tid] += a;
    __syncthreads();
  }
  int ex = ls[tid] - sum;
  #pragma unroll
  for (int j = 0; j < 8; ++j) bbase[tid * 8 + j] = ex + loc[j];
}

// ---------------- binning B: per-bucket local CSR (deg padded to x2)
__global__ __launch_bounds__(256) void binB_kernel(const int* __restrict__ bcnt,
                                                   const int* __restrict__ bbase,
                                                   const unsigned int* __restrict__ bbuf,
                                                   int* __restrict__ cntP,
                                                   int* __restrict__ start,
                                                   int* __restrict__ lst) {
  __shared__ unsigned int ebuf[NREP_ * CAPR_];
  __shared__ int rep_off[NREP_ + 1];
  __shared__ int lcnt[64], loff[64], lcur[64], lcc[64], spd[64];
  int b = blockIdx.x, tid = threadIdx.x;
  if (tid < 64) { lcnt[tid] = 0; lcur[tid] = 0; }
  if (tid == 0) {
    int s = 0;
    for (int r = 0; r < NREP_; ++r) {
      rep_off[r] = s;
      int c = bcnt[r * NBKT_ + b]; c = c < CAPR_ ? c : CAPR_;
      s += c;
    }
    rep_off[NREP_] = s;
  }
  __syncthreads();
  for (int r = 0; r < NREP_; ++r) {
    int c = rep_off[r + 1] - rep_off[r];
    const unsigned int* src = bbuf + ((size_t)b * NREP_ + r) * CAPR_;
    for (int i = tid; i < c; i += 256) {
      unsigned int v = src[i];
      ebuf[rep_off[r] + i] = v;
      atomicAdd(&lcnt[v >> 17], 1);
    }
  }
  __syncthreads();
  int cc = 0, pd = 0;
  if (tid < 64) {
    cc = lcnt[tid]; cc = cc < 64 ? cc : 64;
    pd = (cc + 1) & ~1;
    spd[tid] = pd;
  }
  __syncthreads();
  for (int off = 1; off < 64; off <<= 1) {
    int a = (tid < 64 && tid >= off) ? spd[tid - off] : 0;
    __syncthreads();
    if (tid < 64) spd[tid] += a;
    __syncthreads();
  }
  int bb = bbase[b];
  if (tid < 64) {
    int off = spd[tid] - pd;
    loff[tid] = off; lcc[tid] = cc;
    int node = b * 64 + tid;
    cntP[node] = pd;
    start[node] = bb + off;
  }
  __syncthreads();
  int total = rep_off[NREP_];
  for (int i = tid; i < total; i += 256) {
    unsigned int v = ebuf[i];
    int dl = v >> 17, src = v & 0x1FFFF;
    int p = atomicAdd(&lcur[dl], 1);
    if (p < lcc[dl]) lst[bb + loff[dl] + p] = src;
  }
  __syncthreads();
  if (tid < 64) {
    int base2 = bb + loff[tid];
    int pd2 = (lcc[tid] + 1) & ~1;
    for (int q = lcc[tid]; q < pd2; ++q) lst[base2 + q] = N_;   // sentinel
  }
}

// ---------------- loop-1 aggregation: quarter-wave nodes, 8 loads in flight
__global__ __launch_bounds__(256) void agg1_kernel(const unsigned short* __restrict__ h,
                                                   unsigned short* __restrict__ z,
                                                   const int* __restrict__ start,
                                                   const int* __restrict__ cntP,
                                                   const int* __restrict__ lst,
                                                   const float* __restrict__ eps_ptr,
                                                   int layer) {
  int tid = threadIdx.x;
  int wave = tid >> 6, lane = tid & 63;
  int qw = lane >> 4, ql = lane & 15;
  int node = (blockIdx.x * 4 + wave) * 4 + qw;
  float eps = 1.0f + eps_ptr[layer];
  int pd = cntP[node];
  int b = start[node];
  int idx[4];
  #pragma unroll
  for (int r = 0; r < 4; ++r) {
    int slot = r * 16 + ql;
    idx[r] = (slot < pd) ? lst[b + slot] : N_;
  }
  int it = pd >> 1;
  int itm = it;
  itm = max(itm, __shfl_xor(itm, 16));
  itm = max(itm, __shfl_xor(itm, 32));
  const uint4* h16 = (const uint4*)h;
  float a[8] = {0.f,0.f,0.f,0.f,0.f,0.f,0.f,0.f};
  for (int t = 0; t < itm; t += 4) {          // 8 edges per iteration; j <= 63
    int e[8];
    #pragma unroll
    for (int p = 0; p < 8; ++p) {
      int j = 2 * t + p;
      int r = j >> 4;
      int v = (r == 0) ? idx[0] : (r == 1) ? idx[1] : (r == 2) ? idx[2] : idx[3];
      e[p] = __shfl(v, qw * 16 + (j & 15));
    }
    uint4 w[8];
    #pragma unroll
    for (int p = 0; p < 8; ++p) w[p] = h16[(size_t)e[p] * 16 + ql];
    #pragma unroll
    for (int p = 0; p < 8; ++p) {
      float2 f0 = unpk(w[p].x), f1 = unpk(w[p].y), f2 = unpk(w[p].z), f3 = unpk(w[p].w);
      a[0] += f0.x; a[1] += f0.y; a[2] += f1.x; a[3] += f1.y;
      a[4] += f2.x; a[5] += f2.y; a[6] += f3.x; a[7] += f3.y;
    }
  }
  uint4 self = h16[(size_t)node * 16 + ql];
  float2 s0 = unpk(self.x), s1 = unpk(self.y), s2 = unpk(self.z), s3 = unpk(self.w);
  float o0 = eps * s0.x + a[0], o1 = eps * s0.y + a[1];
  float o2 = eps * s1.x + a[2], o3 = eps * s1.y + a[3];
  float o4 = eps * s2.x + a[4], o5 = eps * s2.y + a[5];
  float o6 = eps * s3.x + a[6], o7 = eps * s3.y + a[7];
  uint4 ov;
  ov.x = ((unsigned int)f2b(o1) << 16) | f2b(o0);
  ov.y = ((unsigned int)f2b(o3) << 16) | f2b(o2);
  ov.z = ((unsigned int)f2b(o5) << 16) | f2b(o4);
  ov.w = ((unsigned int)f2b(o7) << 16) | f2b(o6);
  ((uint4*)z)[(size_t)node * 16 + ql] = ov;
}

// ---------------- loop-2 aggregation: relu(h+c), sentinel -> -big row, 8-wide
__global__ __launch_bounds__(256) void agg2_kernel(const unsigned short* __restrict__ h,
                                                   unsigned short* __restrict__ z,
                                                   const int* __restrict__ start,
                                                   const int* __restrict__ cntP,
                                                   const int* __restrict__ lst,
                                                   const float* __restrict__ cTab,
                                                   const int* __restrict__ los,
                                                   const float* __restrict__ eps_ptr,
                                                   int layer) {
  int tid = threadIdx.x;
  int wave = tid >> 6, lane = tid & 63;
  int qw = lane >> 4, ql = lane & 15;
  int node = (blockIdx.x * 4 + wave) * 4 + qw;
  float eps = 1.0f + eps_ptr[layer];
  int pd = cntP[node];
  int b = start[node];
  int idx[4];
  #pragma unroll
  for (int r = 0; r < 4; ++r) {
    int slot = r * 16 + ql;
    int v = (slot < pd) ? lst[b + slot] : N_;
    idx[r] = v + (v >> 17);                   // sentinel N_ -> N_+1 (-big row)
  }
  int it = pd >> 1;
  int itm = it;
  itm = max(itm, __shfl_xor(itm, 16));
  itm = max(itm, __shfl_xor(itm, 32));
  const uint4* h16 = (const uint4*)h;
  const float4* ct = (const float4*)(cTab + (size_t)layer * 38 * 128);
  float4 cA = ct[ql * 2], cB = ct[ql * 2 + 1];
  float a[8] = {0.f,0.f,0.f,0.f,0.f,0.f,0.f,0.f};
  for (int t = 0; t < itm; t += 4) {          // 8 edges per iteration; j <= 63
    int e[8];
    #pragma unroll
    for (int p = 0; p < 8; ++p) {
      int j = 2 * t + p;
      int r = j >> 4;
      int v = (r == 0) ? idx[0] : (r == 1) ? idx[1] : (r == 2) ? idx[2] : idx[3];
      e[p] = __shfl(v, qw * 16 + (j & 15));
    }
    uint4 w[8];
    #pragma unroll
    for (int p = 0; p < 8; ++p) w[p] = h16[(size_t)e[p] * 16 + ql];
    #pragma unroll
    for (int p = 0; p < 8; ++p) {
      float2 f0 = unpk(w[p].x), f1 = unpk(w[p].y), f2 = unpk(w[p].z), f3 = unpk(w[p].w);
      a[0] += fmaxf(f0.x + cA.x, 0.f); a[1] += fmaxf(f0.y + cA.y, 0.f);
      a[2] += fmaxf(f1.x + cA.z, 0.f); a[3] += fmaxf(f1.y + cA.w, 0.f);
      a[4] += fmaxf(f2.x + cB.x, 0.f); a[5] += fmaxf(f2.y + cB.y, 0.f);
      a[6] += fmaxf(f3.x + cB.z, 0.f); a[7] += fmaxf(f3.y + cB.w, 0.f);
    }
  }
  if (node >= MERGED_) {                      // extra self-edge j -> j+MERGED_
    int jS = node - MERGED_;
    int lt = los[jS >> 8];
    const float4* cr = (const float4*)(cTab + ((size_t)layer * 38 + lt) * 128);
    float4 dA = cr[ql * 2], dB = cr[ql * 2 + 1];
    uint4 v = h16[(size_t)jS * 16 + ql];
    float2 f0 = unpk(v.x), f1 = unpk(v.y), f2 = unpk(v.z), f3 = unpk(v.w);
    a[0] += fmaxf(f0.x + dA.x, 0.f); a[1] += fmaxf(f0.y + dA.y, 0.f);
    a[2] += fmaxf(f1.x + dA.z, 0.f); a[3] += fmaxf(f1.y + dA.w, 0.f);
    a[4] += fmaxf(f2.x + dB.x, 0.f); a[5] += fmaxf(f2.y + dB.y, 0.f);
    a[6] += fmaxf(f3.x + dB.z, 0.f); a[7] += fmaxf(f3.y + dB.w, 0.f);
  }
  uint4 self = h16[(size_t)node * 16 + ql];
  float2 s0 = unpk(self.x), s1 = unpk(self.y), s2 = unpk(self.z), s3 = unpk(self.w);
  float o0 = eps * s0.x + a[0], o1 = eps * s0.y + a[1];
  float o2 = eps * s1.x + a[2], o3 = eps * s1.y + a[3];
  float o4 = eps * s2.x + a[4], o5 = eps * s2.y + a[5];
  float o6 = eps * s3.x + a[6], o7 = eps * s3.y + a[7];
  uint4 ov;
  ov.x = ((unsigned int)f2b(o1) << 16) | f2b(o0);
  ov.y = ((unsigned int)f2b(o3) << 16) | f2b(o2);
  ov.z = ((unsigned int)f2b(o5) << 16) | f2b(o4);
  ov.w = ((unsigned int)f2b(o7) << 16) | f2b(o6);
  ((uint4*)z)[(size_t)node * 16 + ql] = ov;
}

// ---------------- fused MLP (R7/R11-proven: LDS-staged weights, t reuses w1t)
// mode bit0: write hout; bit1: gsum into osum
__global__ __launch_bounds__(256, 2) void mlp_kernel(
    const unsigned short* __restrict__ zin, unsigned short* __restrict__ hout,
    const unsigned short* __restrict__ w1g, const unsigned short* __restrict__ w2g,
    const float* __restrict__ b1, const float* __restrict__ gg,
    const float* __restrict__ be, const float* __restrict__ b2,
    float* __restrict__ osum, int mode) {
  __shared__ __align__(16) unsigned short w1t[128 * LDP_];  // w1^T; reused for t
  __shared__ __align__(16) unsigned short w2t[128 * LDP_];
  __shared__ float b1s[128], gs[128], bes[128], b2s[128], sred[128];

  int tid = threadIdx.x;
  #pragma unroll
  for (int it = 0; it < 8; ++it) {
    int flat = it * 2048 + tid * 8;
    int n = flat >> 7, k = flat & 127;
    *(ushort8*)&w1t[n * LDP_ + k] = *(const ushort8*)(w1g + flat);
    *(ushort8*)&w2t[n * LDP_ + k] = *(const ushort8*)(w2g + flat);
  }
  if (tid < 128) {
    b1s[tid] = b1[tid]; gs[tid] = gg[tid]; bes[tid] = be[tid]; b2s[tid] = b2[tid];
    sred[tid] = 0.f;
  }

  int wave = tid >> 6, lane = tid & 63;
  int quad = lane >> 4, m = lane & 15;
  size_t row0 = (size_t)blockIdx.x * 128 + wave * 32;

  // A-frags for GEMM1 from global bf16 z (overlaps the LDS staging above)
  bf16x8 afr[2][4];
  #pragma unroll
  for (int rb = 0; rb < 2; ++rb) {
    const unsigned short* pr = zin + (row0 + rb * 16 + m) * 128 + quad * 8;
    #pragma unroll
    for (int kc = 0; kc < 4; ++kc)
      afr[rb][kc] = __builtin_bit_cast(bf16x8, *(const ushort8*)(pr + kc * 32));
  }
  __syncthreads();

  f32x4 acc[2][8];
  #pragma unroll
  for (int rb = 0; rb < 2; ++rb)
    #pragma unroll
    for (int cb = 0; cb < 8; ++cb)
      acc[rb][cb] = (f32x4){0.f, 0.f, 0.f, 0.f};

  #pragma unroll
  for (int kc = 0; kc < 4; ++kc) {
    #pragma unroll
    for (int cb = 0; cb < 8; ++cb) {
      bf16x8 bfr = __builtin_bit_cast(bf16x8,
          *(const ushort8*)&w1t[(cb * 16 + m) * LDP_ + kc * 32 + quad * 8]);
      acc[0][cb] = __builtin_amdgcn_mfma_f32_16x16x32_bf16(afr[0][kc], bfr, acc[0][cb], 0, 0, 0);
      acc[1][cb] = __builtin_amdgcn_mfma_f32_16x16x32_bf16(afr[1][kc], bfr, acc[1][cb], 0, 0, 0);
    }
  }

  // bias + LN + ReLU
  #pragma unroll
  for (int rb = 0; rb < 2; ++rb) {
    #pragma unroll
    for (int reg = 0; reg < 4; ++reg) {
      float v[8]; float s1 = 0.f, s2 = 0.f;
      #pragma unroll
      for (int cb = 0; cb < 8; ++cb) {
        float xv = acc[rb][cb][reg] + b1s[cb * 16 + m];
        v[cb] = xv; s1 += xv; s2 += xv * xv;
      }
      #pragma unroll
      for (int off = 1; off < 16; off <<= 1) { s1 += __shfl_xor(s1, off); s2 += __shfl_xor(s2, off); }
      float mu  = s1 * (1.f / 128.f);
      float var = s2 * (1.f / 128.f) - mu * mu;
      float inv = rsqrtf(var + LN_EPS_);
      #pragma unroll
      for (int cb = 0; cb < 8; ++cb) {
        float xn = (v[cb] - mu) * inv * gs[cb * 16 + m] + bes[cb * 16 + m];
        acc[rb][cb][reg] = fmaxf(xn, 0.f);
      }
    }
  }

  __syncthreads();   // all waves done reading w1t -> reuse for t
  int rl0 = wave * 32;
  #pragma unroll
  for (int rb = 0; rb < 2; ++rb)
    #pragma unroll
    for (int cb = 0; cb < 8; ++cb)
      #pragma unroll
      for (int reg = 0; reg < 4; ++reg)
        w1t[(rl0 + rb * 16 + quad * 4 + reg) * LDP_ + cb * 16 + m] = f2b(acc[rb][cb][reg]);

  // t rows are wave-private: no barrier needed before re-reading them
  bf16x8 afr2[2][4];
  #pragma unroll
  for (int rb = 0; rb < 2; ++rb)
    #pragma unroll
    for (int kc = 0; kc < 4; ++kc)
      afr2[rb][kc] = __builtin_bit_cast(bf16x8,
          *(const ushort8*)&w1t[(rl0 + rb * 16 + m) * LDP_ + kc * 32 + quad * 8]);

  f32x4 acc2[2][8];
  #pragma unroll
  for (int rb = 0; rb < 2; ++rb)
    #pragma unroll
    for (int cb = 0; cb < 8; ++cb)
      acc2[rb][cb] = (f32x4){0.f, 0.f, 0.f, 0.f};

  #pragma unroll
  for (int kc = 0; kc < 4; ++kc) {
    #pragma unroll
    for (int cb = 0; cb < 8; ++cb) {
      bf16x8 bfr = __builtin_bit_cast(bf16x8,
          *(const ushort8*)&w2t[(cb * 16 + m) * LDP_ + kc * 32 + quad * 8]);
      acc2[0][cb] = __builtin_amdgcn_mfma_f32_16x16x32_bf16(afr2[0][kc], bfr, acc2[0][cb], 0, 0, 0);
      acc2[1][cb] = __builtin_amdgcn_mfma_f32_16x16x32_bf16(afr2[1][kc], bfr, acc2[1][cb], 0, 0, 0);
    }
  }

  float cs[8];
  #pragma unroll
  for (int cb = 0; cb < 8; ++cb) {
    int col = cb * 16 + m;
    float bb = b2s[col];
    float c = 0.f;
    #pragma unroll
    for (int rb = 0; rb < 2; ++rb)
      #pragma unroll
      for (int reg = 0; reg < 4; ++reg) {
        float v = acc2[rb][cb][reg] + bb;
        if (mode & 1) {
          size_t r = row0 + rb * 16 + quad * 4 + reg;
          hout[r * 128 + col] = f2b(v);
        }
        c += v;
      }
    cs[cb] = c;
  }
  if (mode & 2) {
    #pragma unroll
    for (int cb = 0; cb < 8; ++cb) {
      float s = cs[cb];
      s += __shfl_xor(s, 16);
      s += __shfl_xor(s, 32);
      if (quad == 0) atomicAdd(&sred[cb * 16 + m], s);
    }
    __syncthreads();
    if (tid < 128) atomicAdd(&osum[(size_t)(blockIdx.x >> 1) * 256 + tid], sred[tid]);
  }
}

extern "C" void kernel_launch(void* const* d_in, const int* in_sizes, int n_in,
                              void* d_out, int out_size, void* d_ws, size_t ws_size,
                              hipStream_t stream) {
  const int*   x        = (const int*)d_in[0];
  const int*   ei       = (const int*)d_in[1];
  const int*   los      = (const int*)d_in[2];
  const float* emb      = (const float*)d_in[3];
  const float* lostab   = (const float*)d_in[4];
  const float* g1_w1    = (const float*)d_in[5];
  const float* g1_b1    = (const float*)d_in[6];
  const float* g1_g     = (const float*)d_in[7];
  const float* g1_be    = (const float*)d_in[8];
  const float* g1_w2    = (const float*)d_in[9];
  const float* g1_b2    = (const float*)d_in[10];
  const float* g1_eps   = (const float*)d_in[11];
  const float* g2_w1    = (const float*)d_in[12];
  const float* g2_b1    = (const float*)d_in[13];
  const float* g2_g     = (const float*)d_in[14];
  const float* g2_be    = (const float*)d_in[15];
  const float* g2_w2    = (const float*)d_in[16];
  const float* g2_b2    = (const float*)d_in[17];
  const float* g2_eps   = (const float*)d_in[18];
  const float* g2_ew    = (const float*)d_in[19];
  const float* g2_eb    = (const float*)d_in[20];
  float* out = (float*)d_out;

  char* ws = (char*)d_ws;
  unsigned short* h   = (unsigned short*)(ws);                        // 33,555,456
  unsigned short* z   = (unsigned short*)(ws + (size_t)33555456);     // 33,554,432
  unsigned int* bbuf = (unsigned int*)(ws + (size_t)33555456);        // aliases z
  int* bcnt  = (int*)(ws + (size_t)67109888);                         // 65,536
  int* bbase = (int*)(ws + (size_t)67175424);                         // 8,192
  int* cntP  = (int*)(ws + (size_t)67183616);                         // 524,288
  int* start = (int*)(ws + (size_t)67707904);                         // 524,288
  float* cTab= (float*)(ws + (size_t)68232192);                       // 38,912
  unsigned short* wT = (unsigned short*)(ws + (size_t)68271104);      // 262,144
  int* lst   = (int*)(ws + (size_t)68533248);                         // 8,388,608 -> ends 76,921,856

  hipMemsetAsync(bcnt, 0, (size_t)NREP_ * NBKT_ * 4, stream);
  setup_kernel<<<13389, 256, 0, stream>>>(g1_w1, g1_w2, g2_w1, g2_w2, wT,
                                          lostab, g2_ew, g2_eb, cTab, out,
                                          x, emb, h, ei, bcnt, bbuf);
  bscan_kernel<<<1, 256, 0, stream>>>(bcnt, bbase);
  binB_kernel <<<NBKT_, 256, 0, stream>>>(bcnt, bbase, bbuf, cntP, start, lst);

  for (int i = 0; i < 2; ++i) {
    agg1_kernel<<<8192, 256, 0, stream>>>(h, z, start, cntP, lst, g1_eps, i);
    mlp_kernel <<<1024, 256, 0, stream>>>(z, h,
        wT + (size_t)i * 16384, wT + (size_t)(2 + i) * 16384,
        g1_b1 + i * 128, g1_g + i * 128, g1_be + i * 128, g1_b2 + i * 128,
        out, i == 1 ? 3 : 1);
  }

  for (int i = 0; i < 2; ++i) {
    agg2_kernel<<<8192, 256, 0, stream>>>(h, z, start, cntP, lst, cTab, los, g2_eps, i);
    mlp_kernel <<<1024, 256, 0, stream>>>(z, h,
        wT + (size_t)(4 + i) * 16384, wT + (size_t)(6 + i) * 16384,
        g2_b1 + i * 128, g2_g + i * 128, g2_be + i * 128, g2_b2 + i * 128,
        out + 128, i == 1 ? 2 : 1);
  }
}

// Round 13
// 455.184 us; speedup vs baseline: 1.6800x; 1.0171x over previous
//
#include <hip/hip_runtime.h>

// Problem constants
#define B_        256
#define VOCAB_    100
#define D_        128
#define N_        131072      // 2*B*NUM_NODES
#define E_INT_    1048576     // N*8
#define MERGED_   65536       // B*NUM_NODES
#define LN_EPS_   1e-5f
#define LDP_      136         // padded LDS row (bf16): 128+8
#define NBKT_     2048        // dst buckets (64 nodes each)
#define NREP_     8           // counter/buffer replicas (one per XCD via blk&7)
#define CAPR_     128         // per-replica per-bucket capacity
#define BPAD_     64          // max per-bucket lst padding (x2 degree pad)

typedef __attribute__((ext_vector_type(8))) __bf16 bf16x8;
typedef __attribute__((ext_vector_type(8))) unsigned short ushort8;
typedef __attribute__((ext_vector_type(4))) float f32x4;

__device__ __forceinline__ unsigned short f2b(float f) {
  union { float f; unsigned int u; } c; c.f = f;
  unsigned int b = c.u + 0x7fffu + ((c.u >> 16) & 1u);   // RNE
  return (unsigned short)(b >> 16);
}
__device__ __forceinline__ float2 unpk(unsigned int v) {
  union { unsigned int u; float f; } a, b;
  a.u = v << 16; b.u = v & 0xffff0000u;
  return (float2){a.f, b.f};
}

// ---------------- setup: INTERLEAVED binA+embed (latency/BW co-residency),
// then wtrans + ctab + zero-out tail. bcnt zeroed by memset before dispatch.
__global__ __launch_bounds__(256) void setup_kernel(
    const float* __restrict__ w1a, const float* __restrict__ w2a,
    const float* __restrict__ w1b, const float* __restrict__ w2b,
    unsigned short* __restrict__ wT,
    const float* __restrict__ lt, const float* __restrict__ ew,
    const float* __restrict__ eb, float* __restrict__ cTab,
    float* __restrict__ outz,
    const int* __restrict__ x, const float* __restrict__ emb,
    unsigned short* __restrict__ h,
    const int* __restrict__ ei, int* __restrict__ bcnt,
    unsigned int* __restrict__ bbuf) {
  int blk = blockIdx.x, tid = threadIdx.x;
  if (blk < 12288) {                          // interleave: 1x binA : 2x embed
    int g = blk / 3, r = blk - g * 3;
    if (r == 0) {                             // binA block g (4096 total)
      int e = g * 256 + tid;
      int rep = blk & (NREP_ - 1);            // launch-order XCD heuristic
      int s = ei[e], d = ei[E_INT_ + e];
      int b = d >> 6;
      int pos = atomicAdd(&bcnt[rep * NBKT_ + b], 1);
      if (pos < CAPR_)
        bbuf[((size_t)b * NREP_ + rep) * CAPR_ + pos] =
            ((unsigned int)(d & 63) << 17) | (unsigned int)s;
    } else {                                  // embed block g*2+(r-1) (8192 total)
      int ebk = g * 2 + (r - 1);
      int t = ebk * 256 + tid;
      int row = t >> 4, q = t & 15;
      int col = row & 511;
      int tok = x[row];
      const float4* src = (const float4*)(emb + ((size_t)col * VOCAB_ + tok) * D_) + q * 2;
      float4 v0 = src[0], v1 = src[1];
      ushort8 u;
      u[0] = f2b(v0.x); u[1] = f2b(v0.y); u[2] = f2b(v0.z); u[3] = f2b(v0.w);
      u[4] = f2b(v1.x); u[5] = f2b(v1.y); u[6] = f2b(v1.z); u[7] = f2b(v1.w);
      ((ushort8*)h)[(size_t)row * 16 + q] = u;
    }
  } else if (blk == 12288) {                  // sentinel rows
    if (tid < 16) {
      ushort8 zz = (ushort8){0,0,0,0,0,0,0,0};
      ((ushort8*)h)[(size_t)N_ * 16 + tid] = zz;
    } else if (tid < 32) {
      ushort8 mm = (ushort8){0xFF7F,0xFF7F,0xFF7F,0xFF7F,0xFF7F,0xFF7F,0xFF7F,0xFF7F};
      ((ushort8*)h)[(size_t)(N_ + 1) * 16 + (tid - 16)] = mm;
    }
  } else if (blk < 12801) {                   // wtrans: 512 blocks
    int o = (blk - 12289) * 256 + tid;
    int mi = o >> 14;
    const float* srcs[4] = {w1a, w2a, w1b, w2b};
    const float* p = srcs[mi >> 1] + (mi & 1) * 16384;
    int j = o & 16383, n = j >> 7, k = j & 127;
    wT[o] = f2b(p[k * 128 + n]);
  } else if (blk < 12877) {                   // ctab: 76 blocks
    if (tid < 128) {
      int b2 = blk - 12801;
      int i = b2 / 38, r = b2 % 38, c = tid;
      float acc = eb[i * 128 + c];
      for (int k = 0; k < 8; ++k) acc += lt[r * 8 + k] * ew[(i * 8 + k) * 128 + c];
      cTab[((size_t)i * 38 + r) * 128 + c] = acc;
    }
  } else {                                    // zero out: 512 blocks
    outz[(size_t)(blk - 12877) * 256 + tid] = 0.f;
  }
}

// ---------------- exclusive scan of padded bucket sizes
__global__ __launch_bounds__(256) void bscan_kernel(const int* __restrict__ bcnt,
                                                    int* __restrict__ bbase) {
  __shared__ int ls[256];
  int tid = threadIdx.x;
  int loc[8]; int sum = 0;
  #pragma unroll
  for (int j = 0; j < 8; ++j) {
    int b = tid * 8 + j;
    int v = 0;
    #pragma unroll
    for (int r = 0; r < NREP_; ++r) {
      int c = bcnt[r * NBKT_ + b]; c = c < CAPR_ ? c : CAPR_;
      v += c;
    }
    loc[j] = sum; sum += v + BPAD_;
  }
  ls[tid] = sum;
  __syncthreads();
  for (int off = 1; off < 256; off <<= 1) {
    int a = (tid >= off) ? ls[tid - off] : 0;
    __syncthreads();
    ls[tid] += a;
    __syncthreads();
  }
  int ex = ls[tid] - sum;
  #pragma unroll
  for (int j = 0; j < 8; ++j) bbase[tid * 8 + j] = ex + loc[j];
}

// ---------------- binning B: per-bucket local CSR (deg padded to x2)
__global__ __launch_bounds__(256) void binB_kernel(const int* __restrict__ bcnt,
                                                   const int* __restrict__ bbase,
                                                   const unsigned int* __restrict__ bbuf,
                                                   int* __restrict__ cntP,
                                                   int* __restrict__ start,
                                                   int* __restrict__ lst) {
  __shared__ unsigned int ebuf[NREP_ * CAPR_];
  __shared__ int rep_off[NREP_ + 1];
  __shared__ int lcnt[64], loff[64], lcur[64], lcc[64], spd[64];
  int b = blockIdx.x, tid = threadIdx.x;
  if (tid < 64) { lcnt[tid] = 0; lcur[tid] = 0; }
  if (tid == 0) {
    int s = 0;
    for (int r = 0; r < NREP_; ++r) {
      rep_off[r] = s;
      int c = bcnt[r * NBKT_ + b]; c = c < CAPR_ ? c : CAPR_;
      s += c;
    }
    rep_off[NREP_] = s;
  }
  __syncthreads();
  for (int r = 0; r < NREP_; ++r) {
    int c = rep_off[r + 1] - rep_off[r];
    const unsigned int* src = bbuf + ((size_t)b * NREP_ + r) * CAPR_;
    for (int i = tid; i < c; i += 256) {
      unsigned int v = src[i];
      ebuf[rep_off[r] + i] = v;
      atomicAdd(&lcnt[v >> 17], 1);
    }
  }
  __syncthreads();
  int cc = 0, pd = 0;
  if (tid < 64) {
    cc = lcnt[tid]; cc = cc < 64 ? cc : 64;
    pd = (cc + 1) & ~1;
    spd[tid] = pd;
  }
  __syncthreads();
  for (int off = 1; off < 64; off <<= 1) {
    int a = (tid < 64 && tid >= off) ? spd[tid - off] : 0;
    __syncthreads();
    if (tid < 64) spd[tid] += a;
    __syncthreads();
  }
  int bb = bbase[b];
  if (tid < 64) {
    int off = spd[tid] - pd;
    loff[tid] = off; lcc[tid] = cc;
    int node = b * 64 + tid;
    cntP[node] = pd;
    start[node] = bb + off;
  }
  __syncthreads();
  int total = rep_off[NREP_];
  for (int i = tid; i < total; i += 256) {
    unsigned int v = ebuf[i];
    int dl = v >> 17, src = v & 0x1FFFF;
    int p = atomicAdd(&lcur[dl], 1);
    if (p < lcc[dl]) lst[bb + loff[dl] + p] = src;
  }
  __syncthreads();
  if (tid < 64) {
    int base2 = bb + loff[tid];
    int pd2 = (lcc[tid] + 1) & ~1;
    for (int q = lcc[tid]; q < pd2; ++q) lst[base2 + q] = N_;   // sentinel
  }
}

// ---------------- loop-1 aggregation: quarter-wave nodes, 8 loads in flight
__global__ __launch_bounds__(256) void agg1_kernel(const unsigned short* __restrict__ h,
                                                   unsigned short* __restrict__ z,
                                                   const int* __restrict__ start,
                                                   const int* __restrict__ cntP,
                                                   const int* __restrict__ lst,
                                                   const float* __restrict__ eps_ptr,
                                                   int layer) {
  int tid = threadIdx.x;
  int wave = tid >> 6, lane = tid & 63;
  int qw = lane >> 4, ql = lane & 15;
  int node = (blockIdx.x * 4 + wave) * 4 + qw;
  float eps = 1.0f + eps_ptr[layer];
  int pd = cntP[node];
  int b = start[node];
  int idx[4];
  #pragma unroll
  for (int r = 0; r < 4; ++r) {
    int slot = r * 16 + ql;
    idx[r] = (slot < pd) ? lst[b + slot] : N_;
  }
  int it = pd >> 1;
  int itm = it;
  itm = max(itm, __shfl_xor(itm, 16));
  itm = max(itm, __shfl_xor(itm, 32));
  const uint4* h16 = (const uint4*)h;
  float a[8] = {0.f,0.f,0.f,0.f,0.f,0.f,0.f,0.f};
  for (int t = 0; t < itm; t += 4) {          // 8 edges per iteration; j <= 63
    int e[8];
    #pragma unroll
    for (int p = 0; p < 8; ++p) {
      int j = 2 * t + p;
      int r = j >> 4;
      int v = (r == 0) ? idx[0] : (r == 1) ? idx[1] : (r == 2) ? idx[2] : idx[3];
      e[p] = __shfl(v, qw * 16 + (j & 15));
    }
    uint4 w[8];
    #pragma unroll
    for (int p = 0; p < 8; ++p) w[p] = h16[(size_t)e[p] * 16 + ql];
    #pragma unroll
    for (int p = 0; p < 8; ++p) {
      float2 f0 = unpk(w[p].x), f1 = unpk(w[p].y), f2 = unpk(w[p].z), f3 = unpk(w[p].w);
      a[0] += f0.x; a[1] += f0.y; a[2] += f1.x; a[3] += f1.y;
      a[4] += f2.x; a[5] += f2.y; a[6] += f3.x; a[7] += f3.y;
    }
  }
  uint4 self = h16[(size_t)node * 16 + ql];
  float2 s0 = unpk(self.x), s1 = unpk(self.y), s2 = unpk(self.z), s3 = unpk(self.w);
  float o0 = eps * s0.x + a[0], o1 = eps * s0.y + a[1];
  float o2 = eps * s1.x + a[2], o3 = eps * s1.y + a[3];
  float o4 = eps * s2.x + a[4], o5 = eps * s2.y + a[5];
  float o6 = eps * s3.x + a[6], o7 = eps * s3.y + a[7];
  uint4 ov;
  ov.x = ((unsigned int)f2b(o1) << 16) | f2b(o0);
  ov.y = ((unsigned int)f2b(o3) << 16) | f2b(o2);
  ov.z = ((unsigned int)f2b(o5) << 16) | f2b(o4);
  ov.w = ((unsigned int)f2b(o7) << 16) | f2b(o6);
  ((uint4*)z)[(size_t)node * 16 + ql] = ov;
}

// ---------------- loop-2 aggregation: relu(h+c), sentinel -> -big row, 8-wide
__global__ __launch_bounds__(256) void agg2_kernel(const unsigned short* __restrict__ h,
                                                   unsigned short* __restrict__ z,
                                                   const int* __restrict__ start,
                                                   const int* __restrict__ cntP,
                                                   const int* __restrict__ lst,
                                                   const float* __restrict__ cTab,
                                                   const int* __restrict__ los,
                                                   const float* __restrict__ eps_ptr,
                                                   int layer) {
  int tid = threadIdx.x;
  int wave = tid >> 6, lane = tid & 63;
  int qw = lane >> 4, ql = lane & 15;
  int node = (blockIdx.x * 4 + wave) * 4 + qw;
  float eps = 1.0f + eps_ptr[layer];
  int pd = cntP[node];
  int b = start[node];
  int idx[4];
  #pragma unroll
  for (int r = 0; r < 4; ++r) {
    int slot = r * 16 + ql;
    int v = (slot < pd) ? lst[b + slot] : N_;
    idx[r] = v + (v >> 17);                   // sentinel N_ -> N_+1 (-big row)
  }
  int it = pd >> 1;
  int itm = it;
  itm = max(itm, __shfl_xor(itm, 16));
  itm = max(itm, __shfl_xor(itm, 32));
  const uint4* h16 = (const uint4*)h;
  const float4* ct = (const float4*)(cTab + (size_t)layer * 38 * 128);
  float4 cA = ct[ql * 2], cB = ct[ql * 2 + 1];
  float a[8] = {0.f,0.f,0.f,0.f,0.f,0.f,0.f,0.f};
  for (int t = 0; t < itm; t += 4) {          // 8 edges per iteration; j <= 63
    int e[8];
    #pragma unroll
    for (int p = 0; p < 8; ++p) {
      int j = 2 * t + p;
      int r = j >> 4;
      int v = (r == 0) ? idx[0] : (r == 1) ? idx[1] : (r == 2) ? idx[2] : idx[3];
      e[p] = __shfl(v, qw * 16 + (j & 15));
    }
    uint4 w[8];
    #pragma unroll
    for (int p = 0; p < 8; ++p) w[p] = h16[(size_t)e[p] * 16 + ql];
    #pragma unroll
    for (int p = 0; p < 8; ++p) {
      float2 f0 = unpk(w[p].x), f1 = unpk(w[p].y), f2 = unpk(w[p].z), f3 = unpk(w[p].w);
      a[0] += fmaxf(f0.x + cA.x, 0.f); a[1] += fmaxf(f0.y + cA.y, 0.f);
      a[2] += fmaxf(f1.x + cA.z, 0.f); a[3] += fmaxf(f1.y + cA.w, 0.f);
      a[4] += fmaxf(f2.x + cB.x, 0.f); a[5] += fmaxf(f2.y + cB.y, 0.f);
      a[6] += fmaxf(f3.x + cB.z, 0.f); a[7] += fmaxf(f3.y + cB.w, 0.f);
    }
  }
  if (node >= MERGED_) {                      // extra self-edge j -> j+MERGED_
    int jS = node - MERGED_;
    int lt = los[jS >> 8];
    const float4* cr = (const float4*)(cTab + ((size_t)layer * 38 + lt) * 128);
    float4 dA = cr[ql * 2], dB = cr[ql * 2 + 1];
    uint4 v = h16[(size_t)jS * 16 + ql];
    float2 f0 = unpk(v.x), f1 = unpk(v.y), f2 = unpk(v.z), f3 = unpk(v.w);
    a[0] += fmaxf(f0.x + dA.x, 0.f); a[1] += fmaxf(f0.y + dA.y, 0.f);
    a[2] += fmaxf(f1.x + dA.z, 0.f); a[3] += fmaxf(f1.y + dA.w, 0.f);
    a[4] += fmaxf(f2.x + dB.x, 0.f); a[5] += fmaxf(f2.y + dB.y, 0.f);
    a[6] += fmaxf(f3.x + dB.z, 0.f); a[7] += fmaxf(f3.y + dB.w, 0.f);
  }
  uint4 self = h16[(size_t)node * 16 + ql];
  float2 s0 = unpk(self.x), s1 = unpk(self.y), s2 = unpk(self.z), s3 = unpk(self.w);
  float o0 = eps * s0.x + a[0], o1 = eps * s0.y + a[1];
  float o2 = eps * s1.x + a[2], o3 = eps * s1.y + a[3];
  float o4 = eps * s2.x + a[4], o5 = eps * s2.y + a[5];
  float o6 = eps * s3.x + a[6], o7 = eps * s3.y + a[7];
  uint4 ov;
  ov.x = ((unsigned int)f2b(o1) << 16) | f2b(o0);
  ov.y = ((unsigned int)f2b(o3) << 16) | f2b(o2);
  ov.z = ((unsigned int)f2b(o5) << 16) | f2b(o4);
  ov.w = ((unsigned int)f2b(o7) << 16) | f2b(o6);
  ((uint4*)z)[(size_t)node * 16 + ql] = ov;
}

// ---------------- fused MLP (R7/R11-proven: LDS-staged weights, t reuses w1t)
// mode bit0: write hout; bit1: gsum into osum
__global__ __launch_bounds__(256, 2) void mlp_kernel(
    const unsigned short* __restrict__ zin, unsigned short* __restrict__ hout,
    const unsigned short* __restrict__ w1g, const unsigned short* __restrict__ w2g,
    const float* __restrict__ b1, const float* __restrict__ gg,
    const float* __restrict__ be, const float* __restrict__ b2,
    float* __restrict__ osum, int mode) {
  __shared__ __align__(16) unsigned short w1t[128 * LDP_];  // w1^T; reused for t
  __shared__ __align__(16) unsigned short w2t[128 * LDP_];
  __shared__ float b1s[128], gs[128], bes[128], b2s[128], sred[128];

  int tid = threadIdx.x;
  #pragma unroll
  for (int it = 0; it < 8; ++it) {
    int flat = it * 2048 + tid * 8;
    int n = flat >> 7, k = flat & 127;
    *(ushort8*)&w1t[n * LDP_ + k] = *(const ushort8*)(w1g + flat);
    *(ushort8*)&w2t[n * LDP_ + k] = *(const ushort8*)(w2g + flat);
  }
  if (tid < 128) {
    b1s[tid] = b1[tid]; gs[tid] = gg[tid]; bes[tid] = be[tid]; b2s[tid] = b2[tid];
    sred[tid] = 0.f;
  }

  int wave = tid >> 6, lane = tid & 63;
  int quad = lane >> 4, m = lane & 15;
  size_t row0 = (size_t)blockIdx.x * 128 + wave * 32;

  // A-frags for GEMM1 from global bf16 z (overlaps the LDS staging above)
  bf16x8 afr[2][4];
  #pragma unroll
  for (int rb = 0; rb < 2; ++rb) {
    const unsigned short* pr = zin + (row0 + rb * 16 + m) * 128 + quad * 8;
    #pragma unroll
    for (int kc = 0; kc < 4; ++kc)
      afr[rb][kc] = __builtin_bit_cast(bf16x8, *(const ushort8*)(pr + kc * 32));
  }
  __syncthreads();

  f32x4 acc[2][8];
  #pragma unroll
  for (int rb = 0; rb < 2; ++rb)
    #pragma unroll
    for (int cb = 0; cb < 8; ++cb)
      acc[rb][cb] = (f32x4){0.f, 0.f, 0.f, 0.f};

  #pragma unroll
  for (int kc = 0; kc < 4; ++kc) {
    #pragma unroll
    for (int cb = 0; cb < 8; ++cb) {
      bf16x8 bfr = __builtin_bit_cast(bf16x8,
          *(const ushort8*)&w1t[(cb * 16 + m) * LDP_ + kc * 32 + quad * 8]);
      acc[0][cb] = __builtin_amdgcn_mfma_f32_16x16x32_bf16(afr[0][kc], bfr, acc[0][cb], 0, 0, 0);
      acc[1][cb] = __builtin_amdgcn_mfma_f32_16x16x32_bf16(afr[1][kc], bfr, acc[1][cb], 0, 0, 0);
    }
  }

  // bias + LN + ReLU
  #pragma unroll
  for (int rb = 0; rb < 2; ++rb) {
    #pragma unroll
    for (int reg = 0; reg < 4; ++reg) {
      float v[8]; float s1 = 0.f, s2 = 0.f;
      #pragma unroll
      for (int cb = 0; cb < 8; ++cb) {
        float xv = acc[rb][cb][reg] + b1s[cb * 16 + m];
        v[cb] = xv; s1 += xv; s2 += xv * xv;
      }
      #pragma unroll
      for (int off = 1; off < 16; off <<= 1) { s1 += __shfl_xor(s1, off); s2 += __shfl_xor(s2, off); }
      float mu  = s1 * (1.f / 128.f);
      float var = s2 * (1.f / 128.f) - mu * mu;
      float inv = rsqrtf(var + LN_EPS_);
      #pragma unroll
      for (int cb = 0; cb < 8; ++cb) {
        float xn = (v[cb] - mu) * inv * gs[cb * 16 + m] + bes[cb * 16 + m];
        acc[rb][cb][reg] = fmaxf(xn, 0.f);
      }
    }
  }

  __syncthreads();   // all waves done reading w1t -> reuse for t
  int rl0 = wave * 32;
  #pragma unroll
  for (int rb = 0; rb < 2; ++rb)
    #pragma unroll
    for (int cb = 0; cb < 8; ++cb)
      #pragma unroll
      for (int reg = 0; reg < 4; ++reg)
        w1t[(rl0 + rb * 16 + quad * 4 + reg) * LDP_ + cb * 16 + m] = f2b(acc[rb][cb][reg]);

  // t rows are wave-private: no barrier needed before re-reading them
  bf16x8 afr2[2][4];
  #pragma unroll
  for (int rb = 0; rb < 2; ++rb)
    #pragma unroll
    for (int kc = 0; kc < 4; ++kc)
      afr2[rb][kc] = __builtin_bit_cast(bf16x8,
          *(const ushort8*)&w1t[(rl0 + rb * 16 + m) * LDP_ + kc * 32 + quad * 8]);

  f32x4 acc2[2][8];
  #pragma unroll
  for (int rb = 0; rb < 2; ++rb)
    #pragma unroll
    for (int cb = 0; cb < 8; ++cb)
      acc2[rb][cb] = (f32x4){0.f, 0.f, 0.f, 0.f};

  #pragma unroll
  for (int kc = 0; kc < 4; ++kc) {
    #pragma unroll
    for (int cb = 0; cb < 8; ++cb) {
      bf16x8 bfr = __builtin_bit_cast(bf16x8,
          *(const ushort8*)&w2t[(cb * 16 + m) * LDP_ + kc * 32 + quad * 8]);
      acc2[0][cb] = __builtin_amdgcn_mfma_f32_16x16x32_bf16(afr2[0][kc], bfr, acc2[0][cb], 0, 0, 0);
      acc2[1][cb] = __builtin_amdgcn_mfma_f32_16x16x32_bf16(afr2[1][kc], bfr, acc2[1][cb], 0, 0, 0);
    }
  }

  float cs[8];
  #pragma unroll
  for (int cb = 0; cb < 8; ++cb) {
    int col = cb * 16 + m;
    float bb = b2s[col];
    float c = 0.f;
    #pragma unroll
    for (int rb = 0; rb < 2; ++rb)
      #pragma unroll
      for (int reg = 0; reg < 4; ++reg) {
        float v = acc2[rb][cb][reg] + bb;
        if (mode & 1) {
          size_t r = row0 + rb * 16 + quad * 4 + reg;
          hout[r * 128 + col] = f2b(v);
        }
        c += v;
      }
    cs[cb] = c;
  }
  if (mode & 2) {
    #pragma unroll
    for (int cb = 0; cb < 8; ++cb) {
      float s = cs[cb];
      s += __shfl_xor(s, 16);
      s += __shfl_xor(s, 32);
      if (quad == 0) atomicAdd(&sred[cb * 16 + m], s);
    }
    __syncthreads();
    if (tid < 128) atomicAdd(&osum[(size_t)(blockIdx.x >> 1) * 256 + tid], sred[tid]);
  }
}

extern "C" void kernel_launch(void* const* d_in, const int* in_sizes, int n_in,
                              void* d_out, int out_size, void* d_ws, size_t ws_size,
                              hipStream_t stream) {
  const int*   x        = (const int*)d_in[0];
  const int*   ei       = (const int*)d_in[1];
  const int*   los      = (const int*)d_in[2];
  const float* emb      = (const float*)d_in[3];
  const float* lostab   = (const float*)d_in[4];
  const float* g1_w1    = (const float*)d_in[5];
  const float* g1_b1    = (const float*)d_in[6];
  const float* g1_g     = (const float*)d_in[7];
  const float* g1_be    = (const float*)d_in[8];
  const float* g1_w2    = (const float*)d_in[9];
  const float* g1_b2    = (const float*)d_in[10];
  const float* g1_eps   = (const float*)d_in[11];
  const float* g2_w1    = (const float*)d_in[12];
  const float* g2_b1    = (const float*)d_in[13];
  const float* g2_g     = (const float*)d_in[14];
  const float* g2_be    = (const float*)d_in[15];
  const float* g2_w2    = (const float*)d_in[16];
  const float* g2_b2    = (const float*)d_in[17];
  const float* g2_eps   = (const float*)d_in[18];
  const float* g2_ew    = (const float*)d_in[19];
  const float* g2_eb    = (const float*)d_in[20];
  float* out = (float*)d_out;

  char* ws = (char*)d_ws;
  unsigned short* h   = (unsigned short*)(ws);                        // 33,555,456
  unsigned short* z   = (unsigned short*)(ws + (size_t)33555456);     // 33,554,432
  unsigned int* bbuf = (unsigned int*)(ws + (size_t)33555456);        // aliases z
  int* bcnt  = (int*)(ws + (size_t)67109888);                         // 65,536
  int* bbase = (int*)(ws + (size_t)67175424);                         // 8,192
  int* cntP  = (int*)(ws + (size_t)67183616);                         // 524,288
  int* start = (int*)(ws + (size_t)67707904);                         // 524,288
  float* cTab= (float*)(ws + (size_t)68232192);                       // 38,912
  unsigned short* wT = (unsigned short*)(ws + (size_t)68271104);      // 262,144
  int* lst   = (int*)(ws + (size_t)68533248);                         // 8,388,608 -> ends 76,921,856

  hipMemsetAsync(bcnt, 0, (size_t)NREP_ * NBKT_ * 4, stream);
  setup_kernel<<<13389, 256, 0, stream>>>(g1_w1, g1_w2, g2_w1, g2_w2, wT,
                                          lostab, g2_ew, g2_eb, cTab, out,
                                          x, emb, h, ei, bcnt, bbuf);
  bscan_kernel<<<1, 256, 0, stream>>>(bcnt, bbase);
  binB_kernel <<<NBKT_, 256, 0, stream>>>(bcnt, bbase, bbuf, cntP, start, lst);

  for (int i = 0; i < 2; ++i) {
    agg1_kernel<<<8192, 256, 0, stream>>>(h, z, start, cntP, lst, g1_eps, i);
    mlp_kernel <<<1024, 256, 0, stream>>>(z, h,
        wT + (size_t)i * 16384, wT + (size_t)(2 + i) * 16384,
        g1_b1 + i * 128, g1_g + i * 128, g1_be + i * 128, g1_b2 + i * 128,
        out, i == 1 ? 3 : 1);
  }

  for (int i = 0; i < 2; ++i) {
    agg2_kernel<<<8192, 256, 0, stream>>>(h, z, start, cntP, lst, cTab, los, g2_eps, i);
    mlp_kernel <<<1024, 256, 0, stream>>>(z, h,
        wT + (size_t)(4 + i) * 16384, wT + (size_t)(6 + i) * 16384,
        g2_b1 + i * 128, g2_g + i * 128, g2_be + i * 128, g2_b2 + i * 128,
        out + 128, i == 1 ? 2 : 1);
  }
}